// Round 1
// baseline (1499.970 us; speedup 1.0000x reference)
//
#include <hip/hip_runtime.h>
#include <hip/hip_bf16.h>
#include <math.h>

#define D_MODEL 1024
#define D_INNER 2048
#define D_STATE 128
#define NHEADS 32
#define HEADDIM 64
#define CHUNK 64
#define B_SZ 2
#define LSEQ 2048
#define BL (B_SZ*LSEQ)                              // 4096
#define DPROJ (2*D_INNER + 2*D_STATE + NHEADS)      // 4384
#define CONV_DIM (D_INNER + 2*D_STATE)              // 2304
#define NCHUNK (LSEQ/CHUNK)                         // 32
#define EPSF 1e-5f

__device__ __forceinline__ float siluf(float v){ return v / (1.0f + expf(-v)); }
__device__ __forceinline__ float softplusf(float v){ return v > 20.0f ? v : log1pf(expf(v)); }

// C[m,n] = sum_k A[m,k] * W[n,k]   (A: MxK row-major, W: NxK row-major)
// 128x128 tile, 256 threads, 8x8 per thread, BK=8. M % 128 == 0, K % 8 == 0. N guarded.
__global__ __launch_bounds__(256) void gemm_awt(const float* __restrict__ A,
    const float* __restrict__ W, float* __restrict__ C, int M, int N, int K) {
  __shared__ float As[8][129];
  __shared__ float Ws[8][129];
  const int t  = threadIdx.x;
  const int tx = t & 15, ty = t >> 4;
  const int m0 = blockIdx.y * 128, n0 = blockIdx.x * 128;
  const int lrow = t >> 1, lkq = (t & 1) * 4;
  float acc[8][8] = {};
  for (int k0 = 0; k0 < K; k0 += 8) {
    float4 av = *(const float4*)&A[(size_t)(m0 + lrow) * K + k0 + lkq];
    float4 wv = make_float4(0.f,0.f,0.f,0.f);
    if (n0 + lrow < N) wv = *(const float4*)&W[(size_t)(n0 + lrow) * K + k0 + lkq];
    As[lkq+0][lrow]=av.x; As[lkq+1][lrow]=av.y; As[lkq+2][lrow]=av.z; As[lkq+3][lrow]=av.w;
    Ws[lkq+0][lrow]=wv.x; Ws[lkq+1][lrow]=wv.y; Ws[lkq+2][lrow]=wv.z; Ws[lkq+3][lrow]=wv.w;
    __syncthreads();
    #pragma unroll
    for (int k = 0; k < 8; ++k) {
      float a[8], b[8];
      #pragma unroll
      for (int i=0;i<8;++i) a[i] = As[k][ty*8+i];
      #pragma unroll
      for (int j=0;j<8;++j) b[j] = Ws[k][tx*8+j];
      #pragma unroll
      for (int i=0;i<8;++i)
        #pragma unroll
        for (int j=0;j<8;++j) acc[i][j] += a[i]*b[j];
    }
    __syncthreads();
  }
  #pragma unroll
  for (int i=0;i<8;++i){
    int m = m0 + ty*8 + i;
    #pragma unroll
    for (int j=0;j<8;++j){
      int n = n0 + tx*8 + j;
      if (n < N) C[(size_t)m*N + n] = acc[i][j];
    }
  }
}

__global__ void dt_kernel(const float* __restrict__ zxbcdt, const float* __restrict__ dt_bias,
                          float* __restrict__ dt) {
  int i = blockIdx.x * 256 + threadIdx.x;           // over BL*NHEADS
  if (i >= BL*NHEADS) return;
  int row = i >> 5, h = i & 31;
  float v = zxbcdt[(size_t)row*DPROJ + (2*D_INNER + 2*D_STATE) + h] + dt_bias[h];
  dt[i] = softplusf(v);
}

// A_cum[(b*32+h)*32+c][l] = inclusive cumsum over l of (-exp(A_log[h]) * dt[b, c*64+l, h])
__global__ __launch_bounds__(64) void acum_kernel(const float* __restrict__ dt,
    const float* __restrict__ A_log, float* __restrict__ A_cum) {
  int blk = blockIdx.x;                             // (b*32+h)*32+c
  int c = blk & 31, h = (blk >> 5) & 31, b = blk >> 10;
  int l = threadIdx.x;
  __shared__ float sv[64];
  int row = b*LSEQ + c*CHUNK + l;
  float a = -expf(A_log[h]);
  sv[l] = a * dt[row*NHEADS + h];
  __syncthreads();
  if (l == 0) {
    float s = 0.f;
    for (int i=0;i<64;++i){ s += sv[i]; sv[i] = s; }
  }
  __syncthreads();
  A_cum[blk*64 + l] = sv[l];
}

// causal depthwise conv (K=4) + bias + silu over the xBC slice of zxbcdt
__global__ void conv_kernel(const float* __restrict__ zxbcdt, const float* __restrict__ w,
     const float* __restrict__ bias, float* __restrict__ xBC) {
  int idx = blockIdx.x*256 + threadIdx.x;
  if (idx >= BL*CONV_DIM) return;
  int ch  = idx % CONV_DIM;
  int row = idx / CONV_DIM;                         // b*LSEQ + l
  int l   = row & (LSEQ-1);
  float acc = bias[ch];
  #pragma unroll
  for (int k=0;k<4;++k){
    int li = l + k - 3;
    if (li >= 0) acc += w[ch*4+k] * zxbcdt[(size_t)(row + k - 3)*DPROJ + D_INNER + ch];
  }
  xBC[idx] = siluf(acc);
}

// G[b,c][l][s] = sum_n C[l,n] * B[s,n]   (shared across heads)
__global__ __launch_bounds__(256) void g_kernel(const float* __restrict__ xBC, float* __restrict__ G) {
  int blk = blockIdx.x;                             // b*32 + c
  int b = blk >> 5, c = blk & 31;
  __shared__ float Bs[64][129];
  int t = threadIdx.x;
  int row0 = b*LSEQ + c*CHUNK;
  for (int j=0;j<32;++j){
    int lin = j*256 + t;
    int s = lin >> 7, n = lin & 127;
    Bs[s][n] = xBC[(size_t)(row0+s)*CONV_DIM + D_INNER + n];
  }
  __syncthreads();
  int l = t >> 2, s0 = (t & 3) * 16;
  const float* Cp = &xBC[(size_t)(row0+l)*CONV_DIM + D_INNER + D_STATE];
  float acc[16] = {};
  for (int n=0;n<128;++n){
    float cv = Cp[n];
    #pragma unroll
    for (int j=0;j<16;++j) acc[j] += cv * Bs[s0+j][n];
  }
  float* Gp = &G[(size_t)blk*4096 + l*64 + s0];
  #pragma unroll
  for (int j=0;j<16;++j) Gp[j] = acc[j];
}

// states[(b*32+c)*32+h][p][n] = sum_s B[s,n] * exp(Ac[63]-Ac[s]) * x[s,p]*dt[s]
__global__ __launch_bounds__(256) void states_kernel(const float* __restrict__ xBC,
    const float* __restrict__ dt, const float* __restrict__ A_cum, float* __restrict__ states) {
  int blk = blockIdx.x;                             // (b*32+c)*32+h
  int h = blk & 31, c = (blk>>5)&31, b = blk>>10;
  __shared__ float Bs[64][129];
  __shared__ float xd[64][65];
  __shared__ float Ac[64];
  int t = threadIdx.x;
  int row0 = b*LSEQ + c*CHUNK;
  if (t < 64) Ac[t] = A_cum[((b*32+h)*32 + c)*64 + t];
  __syncthreads();
  float AcL = Ac[63];
  for (int j=0;j<32;++j){
    int lin = j*256+t; int s = lin>>7, n = lin&127;
    Bs[s][n] = xBC[(size_t)(row0+s)*CONV_DIM + D_INNER + n];
  }
  for (int j=0;j<16;++j){
    int lin = j*256+t; int s = lin>>6, p = lin&63;
    int row = row0 + s;
    xd[s][p] = xBC[(size_t)row*CONV_DIM + h*HEADDIM + p] * dt[row*NHEADS+h] * expf(AcL - Ac[s]);
  }
  __syncthreads();
  int n = t & 127, pbase = (t>>7)*32;
  float acc[32] = {};
  for (int s=0;s<64;++s){
    float bv = Bs[s][n];
    #pragma unroll
    for (int j=0;j<32;++j) acc[j] += bv * xd[s][pbase+j];
  }
  float* Sp = &states[(size_t)blk*8192];
  #pragma unroll
  for (int j=0;j<32;++j) Sp[(pbase+j)*128 + n] = acc[j];
}

// in-place inter-chunk scan: states[b,c,h] becomes the state ENTERING chunk c
__global__ __launch_bounds__(256) void scan_kernel(const float* __restrict__ A_cum,
                                                   float* __restrict__ states) {
  int blk = blockIdx.x;                             // b*32+h
  int b = blk >> 5, h = blk & 31;
  int t = threadIdx.x;
  float S[32];
  #pragma unroll
  for (int j=0;j<32;++j) S[j] = 0.f;
  for (int c=0;c<NCHUNK;++c){
    float decay = expf(A_cum[((b*32+h)*32 + c)*64 + 63]);
    float* Sp = &states[(size_t)((b*32+c)*32 + h)*8192];
    #pragma unroll
    for (int j=0;j<32;++j){
      float tmp = Sp[j*256+t];
      Sp[j*256+t] = S[j];
      S[j] = S[j]*decay + tmp;
    }
  }
}

// Y = Y_diag + Y_off + x*D, gated by silu(z) -> y_pre[b,l,2048]
__global__ __launch_bounds__(256) void y_kernel(const float* __restrict__ xBC,
    const float* __restrict__ zxbcdt, const float* __restrict__ dt,
    const float* __restrict__ A_cum, const float* __restrict__ G,
    const float* __restrict__ states, const float* __restrict__ Dp,
    float* __restrict__ y_pre) {
  int blk = blockIdx.x;                             // (b*32+c)*32+h
  int h = blk & 31, c = (blk>>5)&31, b = blk>>10;
  __shared__ float xd[64][65];
  __shared__ float Sin[64][129];
  __shared__ float Ac[64];
  __shared__ float dtl[64];
  int t = threadIdx.x;
  int row0 = b*LSEQ + c*CHUNK;
  if (t < 64){
    Ac[t]  = A_cum[((b*32+h)*32 + c)*64 + t];
    dtl[t] = dt[(row0+t)*NHEADS + h];
  }
  __syncthreads();
  for (int j=0;j<16;++j){
    int lin = j*256+t; int s = lin>>6, p = lin&63;
    xd[s][p] = xBC[(size_t)(row0+s)*CONV_DIM + h*HEADDIM + p] * dtl[s];
  }
  {
    const float* Sg = &states[(size_t)blk*8192];
    for (int j=0;j<32;++j){
      int lin = j*256+t; int p = lin>>7, n = lin&127;
      Sin[p][n] = Sg[lin];
    }
  }
  __syncthreads();
  int l = t >> 2, p0 = (t&3)*16;
  const float* Gp = &G[(size_t)(b*32+c)*4096 + l*64];
  float accD[16] = {};
  for (int s=0;s<=l;++s){
    float w = Gp[s] * expf(Ac[l] - Ac[s]);
    #pragma unroll
    for (int j=0;j<16;++j) accD[j] += w * xd[s][p0+j];
  }
  float accO[16] = {};
  const float* Cp = &xBC[(size_t)(row0+l)*CONV_DIM + D_INNER + D_STATE];
  for (int n=0;n<128;++n){
    float cv = Cp[n];
    #pragma unroll
    for (int j=0;j<16;++j) accO[j] += cv * Sin[p0+j][n];
  }
  float od = expf(Ac[l]);
  float Dh = Dp[h];
  float dti = 1.0f / dtl[l];
  const float* zrow = &zxbcdt[(size_t)(row0+l)*DPROJ + h*HEADDIM];
  float* yrow = &y_pre[(size_t)(row0+l)*D_INNER + h*HEADDIM];
  #pragma unroll
  for (int j=0;j<16;++j){
    int p = p0 + j;
    float yv = accD[j] + od*accO[j] + xd[l][p]*dti*Dh;
    yrow[p] = yv * siluf(zrow[p]);
  }
}

// in-place RMS norm * norm_w over rows of 2048
__global__ __launch_bounds__(256) void rms_kernel(float* __restrict__ y,
                                                  const float* __restrict__ norm_w) {
  int row = blockIdx.x;
  int t = threadIdx.x;
  float v[8];
  float ss = 0.f;
  float* yr = &y[(size_t)row*D_INNER];
  #pragma unroll
  for (int j=0;j<8;++j){ v[j] = yr[j*256+t]; ss += v[j]*v[j]; }
  #pragma unroll
  for (int off=32; off>0; off>>=1) ss += __shfl_down(ss, off, 64);
  __shared__ float wsum[4];
  int wid = t >> 6, lane = t & 63;
  if (lane == 0) wsum[wid] = ss;
  __syncthreads();
  if (t == 0) wsum[0] = rsqrtf((wsum[0]+wsum[1]+wsum[2]+wsum[3])/D_INNER + EPSF);
  __syncthreads();
  float sc = wsum[0];
  #pragma unroll
  for (int j=0;j<8;++j) yr[j*256+t] = v[j]*sc*norm_w[j*256+t];
}

extern "C" void kernel_launch(void* const* d_in, const int* in_sizes, int n_in,
                              void* d_out, int out_size, void* d_ws, size_t ws_size,
                              hipStream_t stream) {
  const float* u       = (const float*)d_in[0];
  const float* W_in    = (const float*)d_in[1];
  const float* conv_w  = (const float*)d_in[2];
  const float* conv_b  = (const float*)d_in[3];
  const float* dt_bias = (const float*)d_in[4];
  const float* A_log   = (const float*)d_in[5];
  const float* Dp      = (const float*)d_in[6];
  const float* norm_w  = (const float*)d_in[7];
  const float* W_out   = (const float*)d_in[8];
  float* out = (float*)d_out;

  float* ws = (float*)d_ws;
  float* zxbcdt = ws;   ws += (size_t)BL*DPROJ;                        // 17,956,864
  float* xBC    = ws;   ws += (size_t)BL*CONV_DIM;                     //  9,437,184
  float* dt     = ws;   ws += (size_t)BL*NHEADS;                       //    131,072
  float* A_cum  = ws;   ws += (size_t)B_SZ*NHEADS*NCHUNK*CHUNK;        //    131,072
  float* G      = ws;   ws += (size_t)B_SZ*NCHUNK*CHUNK*CHUNK;         //    262,144
  float* states = ws;   ws += (size_t)B_SZ*NCHUNK*NHEADS*HEADDIM*D_STATE; // 16,777,216
  float* y_pre  = ws;   ws += (size_t)BL*D_INNER;                      //  8,388,608

  // 1) zxbcdt = u @ W_in.T
  gemm_awt<<<dim3((DPROJ+127)/128, BL/128), 256, 0, stream>>>(u, W_in, zxbcdt, BL, DPROJ, D_MODEL);
  // 2) dt = softplus(raw + bias)
  dt_kernel<<<(BL*NHEADS+255)/256, 256, 0, stream>>>(zxbcdt, dt_bias, dt);
  // 3) per-chunk cumsum of A*dt
  acum_kernel<<<B_SZ*NHEADS*NCHUNK, 64, 0, stream>>>(dt, A_log, A_cum);
  // 4) depthwise conv + silu
  conv_kernel<<<(BL*CONV_DIM+255)/256, 256, 0, stream>>>(zxbcdt, conv_w, conv_b, xBC);
  // 5) G = C B^T per (b,c)
  g_kernel<<<B_SZ*NCHUNK, 256, 0, stream>>>(xBC, G);
  // 6) per-chunk states
  states_kernel<<<B_SZ*NCHUNK*NHEADS, 256, 0, stream>>>(xBC, dt, A_cum, states);
  // 7) inter-chunk scan (in place -> states_in)
  scan_kernel<<<B_SZ*NHEADS, 256, 0, stream>>>(A_cum, states);
  // 8) Y_diag + Y_off + D-term, gate with silu(z)
  y_kernel<<<B_SZ*NCHUNK*NHEADS, 256, 0, stream>>>(xBC, zxbcdt, dt, A_cum, G, states, Dp, y_pre);
  // 9) RMS norm
  rms_kernel<<<BL, 256, 0, stream>>>(y_pre, norm_w);
  // 10) out = y @ W_out.T
  gemm_awt<<<dim3(D_MODEL/128, BL/128), 256, 0, stream>>>(y_pre, W_out, out, BL, D_MODEL, D_INNER);
}

// Round 4
// 499.231 us; speedup vs baseline: 3.0046x; 3.0046x over previous
//
#include <hip/hip_runtime.h>
#include <hip/hip_bf16.h>
#include <math.h>

#define D_MODEL 1024
#define D_INNER 2048
#define D_STATE 128
#define NHEADS 32
#define HEADDIM 64
#define CHUNK 64
#define B_SZ 2
#define LSEQ 2048
#define BL (B_SZ*LSEQ)                              // 4096
#define DPROJ (2*D_INNER + 2*D_STATE + NHEADS)      // 4384
#define CONV_DIM (D_INNER + 2*D_STATE)              // 2304
#define NCHUNK (LSEQ/CHUNK)                         // 32
#define NPAD1 4480                                  // DPROJ padded to x128
#define EPSF 1e-5f

typedef __attribute__((ext_vector_type(8))) _Float16 half8;
typedef __attribute__((ext_vector_type(4))) float f32x4;

__device__ __forceinline__ float siluf(float v){ return v / (1.0f + expf(-v)); }
__device__ __forceinline__ float softplusf(float v){ return v > 20.0f ? v : log1pf(expf(v)); }
__device__ __forceinline__ unsigned short f2h(float x){
  _Float16 h = (_Float16)x;
  union { _Float16 h; unsigned short u; } v; v.h = h;
  return v.u;
}

typedef const __attribute__((address_space(1))) void gvoid_t;
typedef __attribute__((address_space(3))) void lvoid_t;
__device__ __forceinline__ void gl_lds16(const void* gsrc, void* ldst) {
  gvoid_t* g = reinterpret_cast<gvoid_t*>((uintptr_t)gsrc);
  lvoid_t* l = reinterpret_cast<lvoid_t*>((unsigned int)(uintptr_t)ldst);
  __builtin_amdgcn_global_load_lds(g, l, 16, 0, 0);
}

// ---------- fp32 -> fp16 converters ----------
__global__ void cvt_f16(const float* __restrict__ in, unsigned short* __restrict__ out, int n4) {
  int i = blockIdx.x*256 + threadIdx.x;
  if (i >= n4) return;
  float4 v = *(const float4*)(in + (size_t)i*4);
  ushort4 o; o.x=f2h(v.x); o.y=f2h(v.y); o.z=f2h(v.z); o.w=f2h(v.w);
  *(ushort4*)(out + (size_t)i*4) = o;
}

// pad rows beyond rows_in with zeros (kdim4 = K/4)
__global__ void cvt_pad(const float* __restrict__ in, unsigned short* __restrict__ out,
                        int rows_in, int total4, int kdim4) {
  int i = blockIdx.x*256 + threadIdx.x;
  if (i >= total4) return;
  int row = i / kdim4;
  ushort4 o; o.x=0; o.y=0; o.z=0; o.w=0;
  if (row < rows_in) {
    float4 v = *(const float4*)(in + (size_t)i*4);
    o.x=f2h(v.x); o.y=f2h(v.y); o.z=f2h(v.z); o.w=f2h(v.w);
  }
  *(ushort4*)(out + (size_t)i*4) = o;
}

// ---------- fp16 MFMA GEMM: C[m,n] = sum_k A[m,k]*W[n,k] ----------
// A: M x K fp16 row-major (M%128==0), W: Npad x K fp16 row-major (grid.x = Npad/128),
// C: fp32, row stride N (store guarded n<N). K%32==0.
__global__ __launch_bounds__(256) void gemm_f16(const unsigned short* __restrict__ A,
    const unsigned short* __restrict__ W, float* __restrict__ C, int N, int K) {
  __shared__ unsigned short As[128*32];
  __shared__ unsigned short Bs[128*32];
  const int t   = threadIdx.x;
  const int wid = t >> 6, l = t & 63;
  const int m0 = blockIdx.y * 128, n0 = blockIdx.x * 128;
  const int srow = t >> 2;                 // staging row 0..63 (+64 for 2nd issue)
  const int skq  = (t & 3) * 8;            // staging k-offset
  const int wr = wid >> 1, wc = wid & 1;   // wave -> 64x64 quadrant
  const int fr = l & 15, fk = (l >> 4) * 8;
  f32x4 acc[4][4] = {};

  const size_t abase = (size_t)(m0 + srow) * K + skq;
  const size_t bbase = (size_t)(n0 + srow) * K + skq;
  char* dA = (char*)As + wid*1024;
  char* dB = (char*)Bs + wid*1024;

  for (int k0 = 0; k0 < K; k0 += 32) {
    gl_lds16(A + abase + k0,                dA);
    gl_lds16(A + abase + (size_t)64*K + k0, dA + 4096);
    gl_lds16(W + bbase + k0,                dB);
    gl_lds16(W + bbase + (size_t)64*K + k0, dB + 4096);
    __syncthreads();
    half8 af[4], bfr[4];
    #pragma unroll
    for (int m = 0; m < 4; ++m)
      af[m] = *(const half8*)(As + (wr*64 + m*16 + fr)*32 + fk);
    #pragma unroll
    for (int n = 0; n < 4; ++n)
      bfr[n] = *(const half8*)(Bs + (wc*64 + n*16 + fr)*32 + fk);
    #pragma unroll
    for (int m = 0; m < 4; ++m)
      #pragma unroll
      for (int n = 0; n < 4; ++n)
        acc[m][n] = __builtin_amdgcn_mfma_f32_16x16x32_f16(af[m], bfr[n], acc[m][n], 0, 0, 0);
    __syncthreads();
  }

  const int crow = m0 + wr*64 + (l >> 4) * 4;
  const int ccol0 = n0 + wc*64 + fr;
  #pragma unroll
  for (int m = 0; m < 4; ++m) {
    #pragma unroll
    for (int n = 0; n < 4; ++n) {
      int col = ccol0 + n*16;
      if (col < N) {
        float* cp = C + (size_t)(crow + m*16)*N + col;
        #pragma unroll
        for (int j = 0; j < 4; ++j) cp[(size_t)j*N] = acc[m][n][j];
      }
    }
  }
}

// ---------- exact fp32 dt path: dt[row,h] = softplus(u[row,:]·W_in[4352+h,:] + bias[h]) ----------
__global__ __launch_bounds__(256) void dt_gemm(const float* __restrict__ u,
    const float* __restrict__ W_in, const float* __restrict__ dt_bias, float* __restrict__ dt) {
  __shared__ float Wsh[32][129];
  __shared__ float Ush[8][129];
  int t = threadIdx.x;
  int row0 = blockIdx.x * 8;
  int h = t & 31, rs = t >> 5;
  float acc = 0.f;
  for (int k0 = 0; k0 < D_MODEL; k0 += 128) {
    #pragma unroll
    for (int j = 0; j < 16; ++j) {
      int lin = j*256 + t; int hh = lin >> 7, kk = lin & 127;
      Wsh[hh][kk] = W_in[(size_t)(2*D_INNER + 2*D_STATE + hh)*D_MODEL + k0 + kk];
    }
    #pragma unroll
    for (int j = 0; j < 4; ++j) {
      int lin = j*256 + t; int rr = lin >> 7, kk = lin & 127;
      Ush[rr][kk] = u[(size_t)(row0+rr)*D_MODEL + k0 + kk];
    }
    __syncthreads();
    #pragma unroll 4
    for (int k = 0; k < 128; ++k) acc += Ush[rs][k] * Wsh[h][k];
    __syncthreads();
  }
  dt[(row0+rs)*NHEADS + h] = softplusf(acc + dt_bias[h]);
}

// A_cum[(b*32+h)*32+c][l] = inclusive cumsum over l of (-exp(A_log[h]) * dt[b, c*64+l, h])
__global__ __launch_bounds__(64) void acum_kernel(const float* __restrict__ dt,
    const float* __restrict__ A_log, float* __restrict__ A_cum) {
  int blk = blockIdx.x;                             // (b*32+h)*32+c
  int c = blk & 31, h = (blk >> 5) & 31, b = blk >> 10;
  int l = threadIdx.x;
  __shared__ float sv[64];
  int row = b*LSEQ + c*CHUNK + l;
  float a = -expf(A_log[h]);
  sv[l] = a * dt[row*NHEADS + h];
  __syncthreads();
  if (l == 0) {
    float s = 0.f;
    for (int i=0;i<64;++i){ s += sv[i]; sv[i] = s; }
  }
  __syncthreads();
  A_cum[blk*64 + l] = sv[l];
}

// causal depthwise conv (K=4) + bias + silu over the xBC slice of zxbcdt
__global__ void conv_kernel(const float* __restrict__ zxbcdt, const float* __restrict__ w,
     const float* __restrict__ bias, float* __restrict__ xBC) {
  int idx = blockIdx.x*256 + threadIdx.x;
  if (idx >= BL*CONV_DIM) return;
  int ch  = idx % CONV_DIM;
  int row = idx / CONV_DIM;                         // b*LSEQ + l
  int l   = row & (LSEQ-1);
  float acc = bias[ch];
  #pragma unroll
  for (int k=0;k<4;++k){
    int li = l + k - 3;
    if (li >= 0) acc += w[ch*4+k] * zxbcdt[(size_t)(row + k - 3)*DPROJ + D_INNER + ch];
  }
  xBC[idx] = siluf(acc);
}

// G[b,c][l][s] = sum_n C[l,n] * B[s,n]
__global__ __launch_bounds__(256) void g_kernel(const float* __restrict__ xBC, float* __restrict__ G) {
  int blk = blockIdx.x;                             // b*32 + c
  int b = blk >> 5, c = blk & 31;
  __shared__ float Bsh[64][129];
  int t = threadIdx.x;
  int row0 = b*LSEQ + c*CHUNK;
  for (int j=0;j<32;++j){
    int lin = j*256 + t;
    int s = lin >> 7, n = lin & 127;
    Bsh[s][n] = xBC[(size_t)(row0+s)*CONV_DIM + D_INNER + n];
  }
  __syncthreads();
  int l = t >> 2, s0 = (t & 3) * 16;
  const float* Cp = &xBC[(size_t)(row0+l)*CONV_DIM + D_INNER + D_STATE];
  float acc[16] = {};
  for (int n=0;n<128;++n){
    float cv = Cp[n];
    #pragma unroll
    for (int j=0;j<16;++j) acc[j] += cv * Bsh[s0+j][n];
  }
  float* Gp = &G[(size_t)blk*4096 + l*64 + s0];
  #pragma unroll
  for (int j=0;j<16;++j) Gp[j] = acc[j];
}

// states[(b*32+c)*32+h][p][n] = sum_s B[s,n] * exp(Ac[63]-Ac[s]) * x[s,p]*dt[s]
__global__ __launch_bounds__(256) void states_kernel(const float* __restrict__ xBC,
    const float* __restrict__ dt, const float* __restrict__ A_cum, float* __restrict__ states) {
  int blk = blockIdx.x;                             // (b*32+c)*32+h
  int h = blk & 31, c = (blk>>5)&31, b = blk>>10;
  __shared__ float Bsh[64][129];
  __shared__ float xd[64][65];
  __shared__ float Ac[64];
  int t = threadIdx.x;
  int row0 = b*LSEQ + c*CHUNK;
  if (t < 64) Ac[t] = A_cum[((b*32+h)*32 + c)*64 + t];
  __syncthreads();
  float AcL = Ac[63];
  for (int j=0;j<32;++j){
    int lin = j*256+t; int s = lin>>7, n = lin&127;
    Bsh[s][n] = xBC[(size_t)(row0+s)*CONV_DIM + D_INNER + n];
  }
  for (int j=0;j<16;++j){
    int lin = j*256+t; int s = lin>>6, p = lin&63;
    int row = row0 + s;
    xd[s][p] = xBC[(size_t)row*CONV_DIM + h*HEADDIM + p] * dt[row*NHEADS+h] * expf(AcL - Ac[s]);
  }
  __syncthreads();
  int n = t & 127, pbase = (t>>7)*32;
  float acc[32] = {};
  for (int s=0;s<64;++s){
    float bv = Bsh[s][n];
    #pragma unroll
    for (int j=0;j<32;++j) acc[j] += bv * xd[s][pbase+j];
  }
  float* Sp = &states[(size_t)blk*8192];
  #pragma unroll
  for (int j=0;j<32;++j) Sp[(pbase+j)*128 + n] = acc[j];
}

// in-place inter-chunk scan: states[b,c,h] becomes the state ENTERING chunk c
__global__ __launch_bounds__(256) void scan_kernel(const float* __restrict__ A_cum,
                                                   float* __restrict__ states) {
  int blk = blockIdx.x;                             // b*32+h
  int b = blk >> 5, h = blk & 31;
  int t = threadIdx.x;
  float S[32];
  #pragma unroll
  for (int j=0;j<32;++j) S[j] = 0.f;
  for (int c=0;c<NCHUNK;++c){
    float decay = expf(A_cum[((b*32+h)*32 + c)*64 + 63]);
    float* Sp = &states[(size_t)((b*32+c)*32 + h)*8192];
    #pragma unroll
    for (int j=0;j<32;++j){
      float tmp = Sp[j*256+t];
      Sp[j*256+t] = S[j];
      S[j] = S[j]*decay + tmp;
    }
  }
}

// Y = Y_diag + Y_off + x*D, gated by silu(z) -> y_pre[b,l,2048]
__global__ __launch_bounds__(256) void y_kernel(const float* __restrict__ xBC,
    const float* __restrict__ zxbcdt, const float* __restrict__ dt,
    const float* __restrict__ A_cum, const float* __restrict__ G,
    const float* __restrict__ states, const float* __restrict__ Dp,
    float* __restrict__ y_pre) {
  int blk = blockIdx.x;                             // (b*32+c)*32+h
  int h = blk & 31, c = (blk>>5)&31, b = blk>>10;
  __shared__ float xd[64][65];
  __shared__ float Sin[64][129];
  __shared__ float Ac[64];
  __shared__ float dtl[64];
  int t = threadIdx.x;
  int row0 = b*LSEQ + c*CHUNK;
  if (t < 64){
    Ac[t]  = A_cum[((b*32+h)*32 + c)*64 + t];
    dtl[t] = dt[(row0+t)*NHEADS + h];
  }
  __syncthreads();
  for (int j=0;j<16;++j){
    int lin = j*256+t; int s = lin>>6, p = lin&63;
    xd[s][p] = xBC[(size_t)(row0+s)*CONV_DIM + h*HEADDIM + p] * dtl[s];
  }
  {
    const float* Sg = &states[(size_t)blk*8192];
    for (int j=0;j<32;++j){
      int lin = j*256+t; int p = lin>>7, n = lin&127;
      Sin[p][n] = Sg[lin];
    }
  }
  __syncthreads();
  int l = t >> 2, p0 = (t&3)*16;
  const float* Gp = &G[(size_t)(b*32+c)*4096 + l*64];
  float accD[16] = {};
  for (int s=0;s<=l;++s){
    float w = Gp[s] * expf(Ac[l] - Ac[s]);
    #pragma unroll
    for (int j=0;j<16;++j) accD[j] += w * xd[s][p0+j];
  }
  float accO[16] = {};
  const float* Cp = &xBC[(size_t)(row0+l)*CONV_DIM + D_INNER + D_STATE];
  for (int n=0;n<128;++n){
    float cv = Cp[n];
    #pragma unroll
    for (int j=0;j<16;++j) accO[j] += cv * Sin[p0+j][n];
  }
  float od = expf(Ac[l]);
  float Dh = Dp[h];
  float dti = 1.0f / dtl[l];
  const float* zrow = &zxbcdt[(size_t)(row0+l)*DPROJ + h*HEADDIM];
  float* yrow = &y_pre[(size_t)(row0+l)*D_INNER + h*HEADDIM];
  #pragma unroll
  for (int j=0;j<16;++j){
    int p = p0 + j;
    float yv = accD[j] + od*accO[j] + xd[l][p]*dti*Dh;
    yrow[p] = yv * siluf(zrow[p]);
  }
}

// RMS norm * norm_w over rows of 2048, writes fp16 for GEMM2
__global__ __launch_bounds__(256) void rms_kernel(const float* __restrict__ y,
    const float* __restrict__ norm_w, unsigned short* __restrict__ yh) {
  int row = blockIdx.x;
  int t = threadIdx.x;
  float v[8];
  float ss = 0.f;
  const float* yr = &y[(size_t)row*D_INNER];
  #pragma unroll
  for (int j=0;j<8;++j){ v[j] = yr[j*256+t]; ss += v[j]*v[j]; }
  #pragma unroll
  for (int off=32; off>0; off>>=1) ss += __shfl_down(ss, off, 64);
  __shared__ float wsum[4];
  int wid = t >> 6, lane = t & 63;
  if (lane == 0) wsum[wid] = ss;
  __syncthreads();
  if (t == 0) wsum[0] = rsqrtf((wsum[0]+wsum[1]+wsum[2]+wsum[3])/D_INNER + EPSF);
  __syncthreads();
  float sc = wsum[0];
  #pragma unroll
  for (int j=0;j<8;++j) yh[(size_t)row*D_INNER + j*256+t] = f2h(v[j]*sc*norm_w[j*256+t]);
}

extern "C" void kernel_launch(void* const* d_in, const int* in_sizes, int n_in,
                              void* d_out, int out_size, void* d_ws, size_t ws_size,
                              hipStream_t stream) {
  const float* u       = (const float*)d_in[0];
  const float* W_in    = (const float*)d_in[1];
  const float* conv_w  = (const float*)d_in[2];
  const float* conv_b  = (const float*)d_in[3];
  const float* dt_bias = (const float*)d_in[4];
  const float* A_log   = (const float*)d_in[5];
  const float* Dp      = (const float*)d_in[6];
  const float* norm_w  = (const float*)d_in[7];
  const float* W_out   = (const float*)d_in[8];
  float* out = (float*)d_out;

  char* w = (char*)d_ws;
  float* zxbcdt = (float*)w;  w += (size_t)BL*DPROJ*4;                  // 71.8 MB
  float* xBC    = (float*)w;  w += (size_t)BL*CONV_DIM*4;               // 37.7 MB
  float* dt     = (float*)w;  w += (size_t)BL*NHEADS*4;
  float* A_cum  = (float*)w;  w += (size_t)B_SZ*NHEADS*NCHUNK*CHUNK*4;
  float* G      = (float*)w;  w += (size_t)B_SZ*NCHUNK*CHUNK*CHUNK*4;
  float* states = (float*)w;  w += (size_t)B_SZ*NCHUNK*NHEADS*HEADDIM*D_STATE*4; // 67.1 MB
  float* y_pre  = (float*)w;  w += (size_t)BL*D_INNER*4;                // 33.6 MB

  // time-aliased fp16 staging:
  // u_h + Win_h live in y_pre's region (y_pre first written at step 8, after GEMM1)
  unsigned short* u_h   = (unsigned short*)y_pre;                       // 8.4 MB
  unsigned short* Win_h = u_h + (size_t)BL*D_MODEL;                     // 9.2 MB  (17.6 < 33.6 MB ok)
  // y_h + Wout_h live in zxbcdt's region (zxbcdt dead after y_kernel)
  unsigned short* y_h    = (unsigned short*)zxbcdt;                     // 16.8 MB
  unsigned short* Wout_h = y_h + (size_t)BL*D_INNER;                    // 4.2 MB (21 < 71.8 MB ok)

  // converts for GEMM1
  cvt_f16<<<(BL*D_MODEL/4)/256, 256, 0, stream>>>(u, u_h, BL*D_MODEL/4);
  cvt_pad<<<((NPAD1*D_MODEL/4)+255)/256, 256, 0, stream>>>(W_in, Win_h, DPROJ, NPAD1*D_MODEL/4, D_MODEL/4);
  // 1) zxbcdt = u @ W_in.T   (fp16 MFMA)
  gemm_f16<<<dim3(NPAD1/128, BL/128), 256, 0, stream>>>(u_h, Win_h, zxbcdt, DPROJ, D_MODEL);
  // 2) dt exact in fp32
  dt_gemm<<<BL/8, 256, 0, stream>>>(u, W_in, dt_bias, dt);
  // 3) per-chunk cumsum of A*dt
  acum_kernel<<<B_SZ*NHEADS*NCHUNK, 64, 0, stream>>>(dt, A_log, A_cum);
  // 4) depthwise conv + silu
  conv_kernel<<<(BL*CONV_DIM+255)/256, 256, 0, stream>>>(zxbcdt, conv_w, conv_b, xBC);
  // 5) G = C B^T per (b,c)
  g_kernel<<<B_SZ*NCHUNK, 256, 0, stream>>>(xBC, G);
  // 6) per-chunk states
  states_kernel<<<B_SZ*NCHUNK*NHEADS, 256, 0, stream>>>(xBC, dt, A_cum, states);
  // 7) inter-chunk scan (in place -> states_in)
  scan_kernel<<<B_SZ*NHEADS, 256, 0, stream>>>(A_cum, states);
  // 8) Y_diag + Y_off + D-term, gate with silu(z); reads zxbcdt, writes y_pre
  y_kernel<<<B_SZ*NCHUNK*NHEADS, 256, 0, stream>>>(xBC, zxbcdt, dt, A_cum, G, states, Dp, y_pre);
  // convert W_out AFTER y_kernel (Wout_h aliases zxbcdt, now dead)
  cvt_f16<<<(D_MODEL*D_INNER/4)/256, 256, 0, stream>>>(W_out, Wout_h, D_MODEL*D_INNER/4);
  // 9) RMS norm -> fp16 (y_h aliases zxbcdt, dead)
  rms_kernel<<<BL, 256, 0, stream>>>(y_pre, norm_w, y_h);
  // 10) out = y @ W_out.T  (fp16 MFMA)
  gemm_f16<<<dim3(D_MODEL/128, BL/128), 256, 0, stream>>>(y_h, Wout_h, out, D_MODEL, D_INNER);
}

// Round 5
// 357.764 us; speedup vs baseline: 4.1926x; 1.3954x over previous
//
#include <hip/hip_runtime.h>
#include <hip/hip_bf16.h>
#include <math.h>

#define D_MODEL 1024
#define D_INNER 2048
#define D_STATE 128
#define NHEADS 32
#define HEADDIM 64
#define CHUNK 64
#define B_SZ 2
#define LSEQ 2048
#define BL (B_SZ*LSEQ)                              // 4096
#define DPROJ (2*D_INNER + 2*D_STATE + NHEADS)      // 4384
#define CONV_DIM (D_INNER + 2*D_STATE)              // 2304
#define NCHUNK (LSEQ/CHUNK)                         // 32
#define NPAD1 4480                                  // DPROJ padded to x128
#define EPSF 1e-5f

typedef __attribute__((ext_vector_type(8))) _Float16 half8;
typedef __attribute__((ext_vector_type(4))) float f32x4;

__device__ __forceinline__ float siluf(float v){ return v / (1.0f + expf(-v)); }
__device__ __forceinline__ float softplusf(float v){ return v > 20.0f ? v : log1pf(expf(v)); }
__device__ __forceinline__ unsigned short f2h(float x){
  _Float16 h = (_Float16)x;
  union { _Float16 h; unsigned short u; } v; v.h = h;
  return v.u;
}

typedef const __attribute__((address_space(1))) void gvoid_t;
typedef __attribute__((address_space(3))) void lvoid_t;
__device__ __forceinline__ void gl_lds16(const void* gsrc, void* ldst) {
  gvoid_t* g = reinterpret_cast<gvoid_t*>((uintptr_t)gsrc);
  lvoid_t* l = reinterpret_cast<lvoid_t*>((unsigned int)(uintptr_t)ldst);
  __builtin_amdgcn_global_load_lds(g, l, 16, 0, 0);
}

// ---------- fp32 -> fp16 converters ----------
__global__ void cvt_f16(const float* __restrict__ in, unsigned short* __restrict__ out, int n4) {
  int i = blockIdx.x*256 + threadIdx.x;
  if (i >= n4) return;
  float4 v = *(const float4*)(in + (size_t)i*4);
  ushort4 o; o.x=f2h(v.x); o.y=f2h(v.y); o.z=f2h(v.z); o.w=f2h(v.w);
  *(ushort4*)(out + (size_t)i*4) = o;
}

// pad rows beyond rows_in with zeros (kdim4 = K/4)
__global__ void cvt_pad(const float* __restrict__ in, unsigned short* __restrict__ out,
                        int rows_in, int total4, int kdim4) {
  int i = blockIdx.x*256 + threadIdx.x;
  if (i >= total4) return;
  int row = i / kdim4;
  ushort4 o; o.x=0; o.y=0; o.z=0; o.w=0;
  if (row < rows_in) {
    float4 v = *(const float4*)(in + (size_t)i*4);
    o.x=f2h(v.x); o.y=f2h(v.y); o.z=f2h(v.z); o.w=f2h(v.w);
  }
  *(ushort4*)(out + (size_t)i*4) = o;
}

// ---------- fp16 MFMA GEMM: C[m,n] = sum_k A[m,k]*W[n,k] ----------
__global__ __launch_bounds__(256) void gemm_f16(const unsigned short* __restrict__ A,
    const unsigned short* __restrict__ W, float* __restrict__ C, int N, int K) {
  __shared__ unsigned short As[128*32];
  __shared__ unsigned short Bs[128*32];
  const int t   = threadIdx.x;
  const int wid = t >> 6, l = t & 63;
  const int m0 = blockIdx.y * 128, n0 = blockIdx.x * 128;
  const int srow = t >> 2;
  const int skq  = (t & 3) * 8;
  const int wr = wid >> 1, wc = wid & 1;
  const int fr = l & 15, fk = (l >> 4) * 8;
  f32x4 acc[4][4] = {};

  const size_t abase = (size_t)(m0 + srow) * K + skq;
  const size_t bbase = (size_t)(n0 + srow) * K + skq;
  char* dA = (char*)As + wid*1024;
  char* dB = (char*)Bs + wid*1024;

  for (int k0 = 0; k0 < K; k0 += 32) {
    gl_lds16(A + abase + k0,                dA);
    gl_lds16(A + abase + (size_t)64*K + k0, dA + 4096);
    gl_lds16(W + bbase + k0,                dB);
    gl_lds16(W + bbase + (size_t)64*K + k0, dB + 4096);
    __syncthreads();
    half8 af[4], bfr[4];
    #pragma unroll
    for (int m = 0; m < 4; ++m)
      af[m] = *(const half8*)(As + (wr*64 + m*16 + fr)*32 + fk);
    #pragma unroll
    for (int n = 0; n < 4; ++n)
      bfr[n] = *(const half8*)(Bs + (wc*64 + n*16 + fr)*32 + fk);
    #pragma unroll
    for (int m = 0; m < 4; ++m)
      #pragma unroll
      for (int n = 0; n < 4; ++n)
        acc[m][n] = __builtin_amdgcn_mfma_f32_16x16x32_f16(af[m], bfr[n], acc[m][n], 0, 0, 0);
    __syncthreads();
  }

  const int crow = m0 + wr*64 + (l >> 4) * 4;
  const int ccol0 = n0 + wc*64 + fr;
  #pragma unroll
  for (int m = 0; m < 4; ++m) {
    #pragma unroll
    for (int n = 0; n < 4; ++n) {
      int col = ccol0 + n*16;
      if (col < N) {
        float* cp = C + (size_t)(crow + m*16)*N + col;
        #pragma unroll
        for (int j = 0; j < 4; ++j) cp[(size_t)j*N] = acc[m][n][j];
      }
    }
  }
}

// ---------- exact fp32 dt path ----------
__global__ __launch_bounds__(256) void dt_gemm(const float* __restrict__ u,
    const float* __restrict__ W_in, const float* __restrict__ dt_bias, float* __restrict__ dt) {
  __shared__ float Wsh[32][129];
  __shared__ float Ush[8][129];
  int t = threadIdx.x;
  int row0 = blockIdx.x * 8;
  int h = t & 31, rs = t >> 5;
  float acc = 0.f;
  for (int k0 = 0; k0 < D_MODEL; k0 += 128) {
    #pragma unroll
    for (int j = 0; j < 16; ++j) {
      int lin = j*256 + t; int hh = lin >> 7, kk = lin & 127;
      Wsh[hh][kk] = W_in[(size_t)(2*D_INNER + 2*D_STATE + hh)*D_MODEL + k0 + kk];
    }
    #pragma unroll
    for (int j = 0; j < 4; ++j) {
      int lin = j*256 + t; int rr = lin >> 7, kk = lin & 127;
      Ush[rr][kk] = u[(size_t)(row0+rr)*D_MODEL + k0 + kk];
    }
    __syncthreads();
    #pragma unroll 4
    for (int k = 0; k < 128; ++k) acc += Ush[rs][k] * Wsh[h][k];
    __syncthreads();
  }
  dt[(row0+rs)*NHEADS + h] = softplusf(acc + dt_bias[h]);
}

// A_cum[(b*32+h)*32+c][l] = inclusive cumsum over l of (-exp(A_log[h]) * dt[b, c*64+l, h])
__global__ __launch_bounds__(64) void acum_kernel(const float* __restrict__ dt,
    const float* __restrict__ A_log, float* __restrict__ A_cum) {
  int blk = blockIdx.x;                             // (b*32+h)*32+c
  int c = blk & 31, h = (blk >> 5) & 31, b = blk >> 10;
  int l = threadIdx.x;
  __shared__ float sv[64];
  int row = b*LSEQ + c*CHUNK + l;
  float a = -expf(A_log[h]);
  sv[l] = a * dt[row*NHEADS + h];
  __syncthreads();
  if (l == 0) {
    float s = 0.f;
    for (int i=0;i<64;++i){ s += sv[i]; sv[i] = s; }
  }
  __syncthreads();
  A_cum[blk*64 + l] = sv[l];
}

// causal depthwise conv (K=4) + bias + silu over the xBC slice of zxbcdt
__global__ void conv_kernel(const float* __restrict__ zxbcdt, const float* __restrict__ w,
     const float* __restrict__ bias, float* __restrict__ xBC) {
  int idx = blockIdx.x*256 + threadIdx.x;
  if (idx >= BL*CONV_DIM) return;
  int ch  = idx % CONV_DIM;
  int row = idx / CONV_DIM;                         // b*LSEQ + l
  int l   = row & (LSEQ-1);
  float acc = bias[ch];
  #pragma unroll
  for (int k=0;k<4;++k){
    int li = l + k - 3;
    if (li >= 0) acc += w[ch*4+k] * zxbcdt[(size_t)(row + k - 3)*DPROJ + D_INNER + ch];
  }
  xBC[idx] = siluf(acc);
}

// G[b,c][l][s] = sum_n C[l,n] * B[s,n]
__global__ __launch_bounds__(256) void g_kernel(const float* __restrict__ xBC, float* __restrict__ G) {
  int blk = blockIdx.x;                             // b*32 + c
  int b = blk >> 5, c = blk & 31;
  __shared__ float Bsh[64][129];
  int t = threadIdx.x;
  int row0 = b*LSEQ + c*CHUNK;
  for (int j=0;j<32;++j){
    int lin = j*256 + t;
    int s = lin >> 7, n = lin & 127;
    Bsh[s][n] = xBC[(size_t)(row0+s)*CONV_DIM + D_INNER + n];
  }
  __syncthreads();
  int l = t >> 2, s0 = (t & 3) * 16;
  const float* Cp = &xBC[(size_t)(row0+l)*CONV_DIM + D_INNER + D_STATE];
  float acc[16] = {};
  for (int n=0;n<128;++n){
    float cv = Cp[n];
    #pragma unroll
    for (int j=0;j<16;++j) acc[j] += cv * Bsh[s0+j][n];
  }
  float* Gp = &G[(size_t)blk*4096 + l*64 + s0];
  #pragma unroll
  for (int j=0;j<16;++j) Gp[j] = acc[j];
}

// ---------- MFMA states: states[(b,c,h)][p][n] = sum_s xd[s,p]*decay[s] * B[s,n] ----------
__global__ __launch_bounds__(256) void states_mfma(const float* __restrict__ xBC,
    const float* __restrict__ dt, const float* __restrict__ A_cum, float* __restrict__ states) {
  int blk = blockIdx.x;                             // (b*32+c)*32+h
  int h = blk & 31, c = (blk>>5)&31, b = blk>>10;
  __shared__ _Float16 Bt[128][72];                  // [n][s]
  __shared__ _Float16 xdT[64][72];                  // [p][s]
  __shared__ float Ac[64], dtl[64];
  int t = threadIdx.x;
  int wid = t >> 6, ln = t & 63;
  int row0 = b*LSEQ + c*CHUNK;
  if (t < 64){ Ac[t] = A_cum[((b*32+h)*32 + c)*64 + t]; dtl[t] = dt[(row0+t)*NHEADS + h]; }
  __syncthreads();
  float AcL = Ac[63];
  #pragma unroll
  for (int j=0;j<32;++j){
    int lin = j*256+t; int s = lin>>7, n = lin&127;
    Bt[n][s] = (_Float16)xBC[(size_t)(row0+s)*CONV_DIM + D_INNER + n];
  }
  #pragma unroll
  for (int j=0;j<16;++j){
    int lin = j*256+t; int s = lin>>6, p = lin&63;
    xdT[p][s] = (_Float16)(xBC[(size_t)(row0+s)*CONV_DIM + h*HEADDIM + p] * dtl[s] * expf(AcL - Ac[s]));
  }
  __syncthreads();
  const int fr = ln & 15, fk = (ln >> 4) * 8;
  f32x4 acc[4][2] = {};
  #pragma unroll
  for (int ks = 0; ks < 2; ++ks){
    half8 a[4], bb[2];
    #pragma unroll
    for (int pt=0;pt<4;++pt) a[pt] = *(const half8*)&xdT[pt*16+fr][ks*32+fk];
    #pragma unroll
    for (int nt=0;nt<2;++nt) bb[nt] = *(const half8*)&Bt[(wid*2+nt)*16+fr][ks*32+fk];
    #pragma unroll
    for (int pt=0;pt<4;++pt)
      #pragma unroll
      for (int nt=0;nt<2;++nt)
        acc[pt][nt] = __builtin_amdgcn_mfma_f32_16x16x32_f16(a[pt], bb[nt], acc[pt][nt], 0, 0, 0);
  }
  float* Sp = &states[(size_t)blk*8192];
  #pragma unroll
  for (int pt=0;pt<4;++pt){
    int p0 = pt*16 + (ln>>4)*4;
    #pragma unroll
    for (int nt=0;nt<2;++nt){
      int n = (wid*2+nt)*16 + fr;
      #pragma unroll
      for (int j=0;j<4;++j) Sp[(p0+j)*128 + n] = acc[pt][nt][j];
    }
  }
}

// in-place inter-chunk scan: states[b,c,h] becomes the state ENTERING chunk c
__global__ __launch_bounds__(256) void scan_kernel(const float* __restrict__ A_cum,
                                                   float* __restrict__ states) {
  int blk = blockIdx.x;                             // b*32+h
  int b = blk >> 5, h = blk & 31;
  int t = threadIdx.x;
  float S[32];
  #pragma unroll
  for (int j=0;j<32;++j) S[j] = 0.f;
  for (int c=0;c<NCHUNK;++c){
    float decay = expf(A_cum[((b*32+h)*32 + c)*64 + 63]);
    float* Sp = &states[(size_t)((b*32+c)*32 + h)*8192];
    #pragma unroll
    for (int j=0;j<32;++j){
      float tmp = Sp[j*256+t];
      Sp[j*256+t] = S[j];
      S[j] = S[j]*decay + tmp;
    }
  }
}

// ---------- MFMA Y: y_pre[l,p] = (Coff·Sin + M·xd + x*D) * silu(z) ----------
__global__ __launch_bounds__(256) void y_mfma(const float* __restrict__ xBC,
    const float* __restrict__ zxbcdt, const float* __restrict__ dt,
    const float* __restrict__ A_cum, const float* __restrict__ G,
    const float* __restrict__ states, const float* __restrict__ Dp,
    float* __restrict__ y_pre) {
  int blk = blockIdx.x;                             // (b*32+c)*32+h
  int h = blk & 31, c = (blk>>5)&31, b = blk>>10;
  __shared__ _Float16 Cl[64][136];                  // [l][n], * exp(Ac[l])
  __shared__ _Float16 Sin[64][136];                 // [p][n]
  __shared__ _Float16 Ms[64][72];                   // [l][s], masked decay * G
  __shared__ _Float16 xdT[64][72];                  // [p][s]
  __shared__ float Ac[64], dtl[64];
  int t = threadIdx.x;
  int wid = t >> 6, ln = t & 63;
  int row0 = b*LSEQ + c*CHUNK;
  if (t < 64){ Ac[t] = A_cum[((b*32+h)*32 + c)*64 + t]; dtl[t] = dt[(row0+t)*NHEADS + h]; }
  __syncthreads();
  #pragma unroll
  for (int j=0;j<32;++j){
    int lin = j*256+t; int l = lin>>7, n = lin&127;
    Cl[l][n] = (_Float16)(xBC[(size_t)(row0+l)*CONV_DIM + D_INNER + D_STATE + n] * expf(Ac[l]));
  }
  {
    const float* Sg = &states[(size_t)blk*8192];
    #pragma unroll
    for (int j=0;j<32;++j){
      int lin = j*256+t; int p = lin>>7, n = lin&127;
      Sin[p][n] = (_Float16)Sg[lin];
    }
  }
  #pragma unroll
  for (int j=0;j<16;++j){
    int lin = j*256+t; int s = lin>>6, p = lin&63;
    xdT[p][s] = (_Float16)(xBC[(size_t)(row0+s)*CONV_DIM + h*HEADDIM + p] * dtl[s]);
  }
  {
    const float* Gp = &G[(size_t)(b*32+c)*4096];
    #pragma unroll
    for (int j=0;j<16;++j){
      int lin = j*256+t; int l = lin>>6, s = lin&63;
      Ms[l][s] = (s <= l) ? (_Float16)(Gp[l*64+s] * expf(Ac[l]-Ac[s])) : (_Float16)0.f;
    }
  }
  __syncthreads();
  const int wr = wid >> 1, wc = wid & 1;
  const int fr = ln & 15, fk = (ln >> 4) * 8;
  f32x4 acc[2][2] = {};
  #pragma unroll
  for (int ks = 0; ks < 4; ++ks){                   // Y_off over n=128
    half8 a[2], bb[2];
    #pragma unroll
    for (int lt=0;lt<2;++lt) a[lt] = *(const half8*)&Cl[(wr*2+lt)*16+fr][ks*32+fk];
    #pragma unroll
    for (int pt=0;pt<2;++pt) bb[pt] = *(const half8*)&Sin[(wc*2+pt)*16+fr][ks*32+fk];
    #pragma unroll
    for (int lt=0;lt<2;++lt)
      #pragma unroll
      for (int pt=0;pt<2;++pt)
        acc[lt][pt] = __builtin_amdgcn_mfma_f32_16x16x32_f16(a[lt], bb[pt], acc[lt][pt], 0, 0, 0);
  }
  #pragma unroll
  for (int ks = 0; ks < 2; ++ks){                   // Y_diag over s=64
    half8 a[2], bb[2];
    #pragma unroll
    for (int lt=0;lt<2;++lt) a[lt] = *(const half8*)&Ms[(wr*2+lt)*16+fr][ks*32+fk];
    #pragma unroll
    for (int pt=0;pt<2;++pt) bb[pt] = *(const half8*)&xdT[(wc*2+pt)*16+fr][ks*32+fk];
    #pragma unroll
    for (int lt=0;lt<2;++lt)
      #pragma unroll
      for (int pt=0;pt<2;++pt)
        acc[lt][pt] = __builtin_amdgcn_mfma_f32_16x16x32_f16(a[lt], bb[pt], acc[lt][pt], 0, 0, 0);
  }
  float Dh = Dp[h];
  #pragma unroll
  for (int lt=0;lt<2;++lt){
    int l0 = (wr*2+lt)*16 + (ln>>4)*4;
    #pragma unroll
    for (int pt=0;pt<2;++pt){
      int p = (wc*2+pt)*16 + fr;
      #pragma unroll
      for (int j=0;j<4;++j){
        int grow = row0 + l0 + j;
        float x = xBC[(size_t)grow*CONV_DIM + h*HEADDIM + p];
        float z = zxbcdt[(size_t)grow*DPROJ + h*HEADDIM + p];
        y_pre[(size_t)grow*D_INNER + h*HEADDIM + p] = (acc[lt][pt][j] + x*Dh) * siluf(z);
      }
    }
  }
}

// RMS norm * norm_w over rows of 2048, writes fp16 for GEMM2
__global__ __launch_bounds__(256) void rms_kernel(const float* __restrict__ y,
    const float* __restrict__ norm_w, unsigned short* __restrict__ yh) {
  int row = blockIdx.x;
  int t = threadIdx.x;
  float v[8];
  float ss = 0.f;
  const float* yr = &y[(size_t)row*D_INNER];
  #pragma unroll
  for (int j=0;j<8;++j){ v[j] = yr[j*256+t]; ss += v[j]*v[j]; }
  #pragma unroll
  for (int off=32; off>0; off>>=1) ss += __shfl_down(ss, off, 64);
  __shared__ float wsum[4];
  int wid = t >> 6, lane = t & 63;
  if (lane == 0) wsum[wid] = ss;
  __syncthreads();
  if (t == 0) wsum[0] = rsqrtf((wsum[0]+wsum[1]+wsum[2]+wsum[3])/D_INNER + EPSF);
  __syncthreads();
  float sc = wsum[0];
  #pragma unroll
  for (int j=0;j<8;++j) yh[(size_t)row*D_INNER + j*256+t] = f2h(v[j]*sc*norm_w[j*256+t]);
}

extern "C" void kernel_launch(void* const* d_in, const int* in_sizes, int n_in,
                              void* d_out, int out_size, void* d_ws, size_t ws_size,
                              hipStream_t stream) {
  const float* u       = (const float*)d_in[0];
  const float* W_in    = (const float*)d_in[1];
  const float* conv_w  = (const float*)d_in[2];
  const float* conv_b  = (const float*)d_in[3];
  const float* dt_bias = (const float*)d_in[4];
  const float* A_log   = (const float*)d_in[5];
  const float* Dp      = (const float*)d_in[6];
  const float* norm_w  = (const float*)d_in[7];
  const float* W_out   = (const float*)d_in[8];
  float* out = (float*)d_out;

  char* w = (char*)d_ws;
  float* zxbcdt = (float*)w;  w += (size_t)BL*DPROJ*4;                  // 71.8 MB
  float* xBC    = (float*)w;  w += (size_t)BL*CONV_DIM*4;               // 37.7 MB
  float* dt     = (float*)w;  w += (size_t)BL*NHEADS*4;
  float* A_cum  = (float*)w;  w += (size_t)B_SZ*NHEADS*NCHUNK*CHUNK*4;
  float* G      = (float*)w;  w += (size_t)B_SZ*NCHUNK*CHUNK*CHUNK*4;
  float* states = (float*)w;  w += (size_t)B_SZ*NCHUNK*NHEADS*HEADDIM*D_STATE*4; // 67.1 MB
  float* y_pre  = (float*)w;  w += (size_t)BL*D_INNER*4;                // 33.6 MB

  // time-aliased fp16 staging:
  unsigned short* u_h   = (unsigned short*)y_pre;                       // in y_pre region
  unsigned short* Win_h = u_h + (size_t)BL*D_MODEL;
  unsigned short* y_h    = (unsigned short*)zxbcdt;                     // in zxbcdt region
  unsigned short* Wout_h = y_h + (size_t)BL*D_INNER;

  cvt_f16<<<(BL*D_MODEL/4)/256, 256, 0, stream>>>(u, u_h, BL*D_MODEL/4);
  cvt_pad<<<((NPAD1*D_MODEL/4)+255)/256, 256, 0, stream>>>(W_in, Win_h, DPROJ, NPAD1*D_MODEL/4, D_MODEL/4);
  // 1) zxbcdt = u @ W_in.T   (fp16 MFMA)
  gemm_f16<<<dim3(NPAD1/128, BL/128), 256, 0, stream>>>(u_h, Win_h, zxbcdt, DPROJ, D_MODEL);
  // 2) dt exact in fp32
  dt_gemm<<<BL/8, 256, 0, stream>>>(u, W_in, dt_bias, dt);
  // 3) per-chunk cumsum of A*dt
  acum_kernel<<<B_SZ*NHEADS*NCHUNK, 64, 0, stream>>>(dt, A_log, A_cum);
  // 4) depthwise conv + silu
  conv_kernel<<<(BL*CONV_DIM+255)/256, 256, 0, stream>>>(zxbcdt, conv_w, conv_b, xBC);
  // 5) G = C B^T per (b,c)
  g_kernel<<<B_SZ*NCHUNK, 256, 0, stream>>>(xBC, G);
  // 6) per-chunk states (MFMA)
  states_mfma<<<B_SZ*NCHUNK*NHEADS, 256, 0, stream>>>(xBC, dt, A_cum, states);
  // 7) inter-chunk scan (in place -> states_in)
  scan_kernel<<<B_SZ*NHEADS, 256, 0, stream>>>(A_cum, states);
  // 8) Y_diag + Y_off + D-term, gate with silu(z) (MFMA)
  y_mfma<<<B_SZ*NCHUNK*NHEADS, 256, 0, stream>>>(xBC, zxbcdt, dt, A_cum, G, states, Dp, y_pre);
  // convert W_out AFTER y_mfma (Wout_h aliases zxbcdt, now dead)
  cvt_f16<<<(D_MODEL*D_INNER/4)/256, 256, 0, stream>>>(W_out, Wout_h, D_MODEL*D_INNER/4);
  // 9) RMS norm -> fp16 (y_h aliases zxbcdt, dead)
  rms_kernel<<<BL, 256, 0, stream>>>(y_pre, norm_w, y_h);
  // 10) out = y @ W_out.T  (fp16 MFMA)
  gemm_f16<<<dim3(D_MODEL/128, BL/128), 256, 0, stream>>>(y_h, Wout_h, out, D_MODEL, D_INNER);
}

// Round 6
// 349.491 us; speedup vs baseline: 4.2919x; 1.0237x over previous
//
#include <hip/hip_runtime.h>
#include <hip/hip_bf16.h>
#include <math.h>

#define D_MODEL 1024
#define D_INNER 2048
#define D_STATE 128
#define NHEADS 32
#define HEADDIM 64
#define CHUNK 64
#define B_SZ 2
#define LSEQ 2048
#define BL (B_SZ*LSEQ)                              // 4096
#define DPROJ (2*D_INNER + 2*D_STATE + NHEADS)      // 4384
#define CONV_DIM (D_INNER + 2*D_STATE)              // 2304
#define NCHUNK (LSEQ/CHUNK)                         // 32
#define NPAD1 4480                                  // DPROJ padded to x128
#define EPSF 1e-5f

typedef __attribute__((ext_vector_type(8))) _Float16 half8;
typedef __attribute__((ext_vector_type(4))) float f32x4;

__device__ __forceinline__ float siluf(float v){ return v / (1.0f + expf(-v)); }
__device__ __forceinline__ float softplusf(float v){ return v > 20.0f ? v : log1pf(expf(v)); }
__device__ __forceinline__ unsigned short f2h(float x){
  _Float16 h = (_Float16)x;
  union { _Float16 h; unsigned short u; } v; v.h = h;
  return v.u;
}

typedef const __attribute__((address_space(1))) void gvoid_t;
typedef __attribute__((address_space(3))) void lvoid_t;
__device__ __forceinline__ void gl_lds16(const void* gsrc, void* ldst) {
  gvoid_t* g = reinterpret_cast<gvoid_t*>((uintptr_t)gsrc);
  lvoid_t* l = reinterpret_cast<lvoid_t*>((unsigned int)(uintptr_t)ldst);
  __builtin_amdgcn_global_load_lds(g, l, 16, 0, 0);
}

// ---------- fp32 -> fp16 converters ----------
__global__ void cvt_f16(const float* __restrict__ in, unsigned short* __restrict__ out, int n4) {
  int i = blockIdx.x*256 + threadIdx.x;
  if (i >= n4) return;
  float4 v = *(const float4*)(in + (size_t)i*4);
  ushort4 o; o.x=f2h(v.x); o.y=f2h(v.y); o.z=f2h(v.z); o.w=f2h(v.w);
  *(ushort4*)(out + (size_t)i*4) = o;
}

__global__ void cvt_pad(const float* __restrict__ in, unsigned short* __restrict__ out,
                        int rows_in, int total4, int kdim4) {
  int i = blockIdx.x*256 + threadIdx.x;
  if (i >= total4) return;
  int row = i / kdim4;
  ushort4 o; o.x=0; o.y=0; o.z=0; o.w=0;
  if (row < rows_in) {
    float4 v = *(const float4*)(in + (size_t)i*4);
    o.x=f2h(v.x); o.y=f2h(v.y); o.z=f2h(v.z); o.w=f2h(v.w);
  }
  *(ushort4*)(out + (size_t)i*4) = o;
}

// ---------- pipelined fp16 MFMA GEMM: C[m,n] = sum_k A[m,k]*W[n,k] ----------
// 128x128 tile, BK=32, 3 LDS slots, 2-tile-deep prefetch, counted vmcnt,
// granule XOR-swizzle (pre-swizzled global source + swizzled ds_read),
// XCD-chunked block swizzle. Grid (N/128, M/128), nwg % 8 == 0.
__global__ __launch_bounds__(256) void gemm_f16_pipe(const unsigned short* __restrict__ A,
    const unsigned short* __restrict__ W, float* __restrict__ C, int N, int K) {
  __shared__ unsigned short lds[3*2*4096];          // [slot][A/B][128*32] = 48 KB
  const int t   = threadIdx.x;
  const int wid = t >> 6, l = t & 63;
  const int nwg = gridDim.x * gridDim.y;
  int bid = blockIdx.y * gridDim.x + blockIdx.x;
  int swz = (bid & 7) * (nwg >> 3) + (bid >> 3);    // XCD-chunked (nwg%8==0)
  const int m0 = (swz / gridDim.x) * 128;
  const int n0 = (swz % gridDim.x) * 128;
  const int wr = wid >> 1, wc = wid & 1;
  const int fr = l & 15, cg = l >> 4;
  const int NT = K >> 5;

  // staging source (2 granules per matrix per thread), inverse-swizzled column
  int srow[2]; int scol[2];
  #pragma unroll
  for (int i=0;i<2;++i){
    int s = i*256 + t;
    int r = s >> 2, c = s & 3;
    int sw = (r + (r>>2)) & 3;
    srow[i] = r; scol[i] = (c ^ sw) * 8;
  }
  const unsigned short* Abase = A + (size_t)m0 * K;
  const unsigned short* Wbase = W + (size_t)n0 * K;

#define STAGE(tt, slot) { \
    int kk = (tt) << 5; \
    unsigned short* La = &lds[(slot)*8192]; \
    unsigned short* Lb = &lds[(slot)*8192 + 4096]; \
    gl_lds16(Abase + (size_t)srow[0]*K + kk + scol[0], (char*)La + (0*256+t)*16); \
    gl_lds16(Abase + (size_t)srow[1]*K + kk + scol[1], (char*)La + (1*256+t)*16); \
    gl_lds16(Wbase + (size_t)srow[0]*K + kk + scol[0], (char*)Lb + (0*256+t)*16); \
    gl_lds16(Wbase + (size_t)srow[1]*K + kk + scol[1], (char*)Lb + (1*256+t)*16); \
  }

  f32x4 acc[4][4] = {};
  STAGE(0, 0);
  STAGE(1, 1);
  asm volatile("s_waitcnt vmcnt(4)" ::: "memory");
  __builtin_amdgcn_s_barrier();
  asm volatile("" ::: "memory");

  for (int tt = 0; tt < NT; ++tt) {
    int slot = tt % 3;
    if (tt + 2 < NT) STAGE(tt+2, (tt+2)%3);
    const unsigned short* La = &lds[slot*8192];
    const unsigned short* Lb = &lds[slot*8192 + 4096];
    half8 af[4], bfv[4];
    #pragma unroll
    for (int m=0;m<4;++m){
      int r = wr*64 + m*16 + fr;
      int sw = (r + (r>>2)) & 3;
      af[m] = *(const half8*)&La[(r*4 + (cg ^ sw))*8];
    }
    #pragma unroll
    for (int n=0;n<4;++n){
      int r = wc*64 + n*16 + fr;
      int sw = (r + (r>>2)) & 3;
      bfv[n] = *(const half8*)&Lb[(r*4 + (cg ^ sw))*8];
    }
    __builtin_amdgcn_s_setprio(1);
    #pragma unroll
    for (int m=0;m<4;++m)
      #pragma unroll
      for (int n=0;n<4;++n)
        acc[m][n] = __builtin_amdgcn_mfma_f32_16x16x32_f16(af[m], bfv[n], acc[m][n], 0, 0, 0);
    __builtin_amdgcn_s_setprio(0);
    if (tt + 2 < NT) { asm volatile("s_waitcnt vmcnt(4)" ::: "memory"); }
    else             { asm volatile("s_waitcnt vmcnt(0)" ::: "memory"); }
    __builtin_amdgcn_s_barrier();
    asm volatile("" ::: "memory");
  }
#undef STAGE

  const int crow = m0 + wr*64 + (l >> 4) * 4;
  const int ccol0 = n0 + wc*64 + fr;
  #pragma unroll
  for (int m = 0; m < 4; ++m) {
    #pragma unroll
    for (int n = 0; n < 4; ++n) {
      int col = ccol0 + n*16;
      if (col < N) {
        float* cp = C + (size_t)(crow + m*16)*N + col;
        #pragma unroll
        for (int j = 0; j < 4; ++j) cp[(size_t)j*N] = acc[m][n][j];
      }
    }
  }
}

// ---------- exact fp32 dt path ----------
__global__ __launch_bounds__(256) void dt_gemm(const float* __restrict__ u,
    const float* __restrict__ W_in, const float* __restrict__ dt_bias, float* __restrict__ dt) {
  __shared__ float Wsh[32][129];
  __shared__ float Ush[8][129];
  int t = threadIdx.x;
  int row0 = blockIdx.x * 8;
  int h = t & 31, rs = t >> 5;
  float acc = 0.f;
  for (int k0 = 0; k0 < D_MODEL; k0 += 128) {
    #pragma unroll
    for (int j = 0; j < 16; ++j) {
      int lin = j*256 + t; int hh = lin >> 7, kk = lin & 127;
      Wsh[hh][kk] = W_in[(size_t)(2*D_INNER + 2*D_STATE + hh)*D_MODEL + k0 + kk];
    }
    #pragma unroll
    for (int j = 0; j < 4; ++j) {
      int lin = j*256 + t; int rr = lin >> 7, kk = lin & 127;
      Ush[rr][kk] = u[(size_t)(row0+rr)*D_MODEL + k0 + kk];
    }
    __syncthreads();
    #pragma unroll 4
    for (int k = 0; k < 128; ++k) acc += Ush[rs][k] * Wsh[h][k];
    __syncthreads();
  }
  dt[(row0+rs)*NHEADS + h] = softplusf(acc + dt_bias[h]);
}

// A_cum[(b*32+h)*32+c][l] = inclusive cumsum over l of (-exp(A_log[h]) * dt[b, c*64+l, h])
__global__ __launch_bounds__(64) void acum_kernel(const float* __restrict__ dt,
    const float* __restrict__ A_log, float* __restrict__ A_cum) {
  int blk = blockIdx.x;                             // (b*32+h)*32+c
  int c = blk & 31, h = (blk >> 5) & 31, b = blk >> 10;
  int l = threadIdx.x;
  __shared__ float sv[64];
  int row = b*LSEQ + c*CHUNK + l;
  float a = -expf(A_log[h]);
  sv[l] = a * dt[row*NHEADS + h];
  __syncthreads();
  if (l == 0) {
    float s = 0.f;
    for (int i=0;i<64;++i){ s += sv[i]; sv[i] = s; }
  }
  __syncthreads();
  A_cum[blk*64 + l] = sv[l];
}

// causal depthwise conv (K=4) + bias + silu, float4 over channels
__global__ void conv4_kernel(const float* __restrict__ zxbcdt, const float* __restrict__ w,
     const float* __restrict__ bias, float* __restrict__ xBC) {
  int idx = blockIdx.x*256 + threadIdx.x;           // over BL * (CONV_DIM/4)
  if (idx >= BL*(CONV_DIM/4)) return;
  int c4  = idx % (CONV_DIM/4);
  int row = idx / (CONV_DIM/4);
  int ch  = c4 * 4;
  int l   = row & (LSEQ-1);
  float4 acc = *(const float4*)&bias[ch];
  #pragma unroll
  for (int k=0;k<4;++k){
    int li = l + k - 3;
    if (li >= 0) {
      float4 v = *(const float4*)&zxbcdt[(size_t)(row + k - 3)*DPROJ + D_INNER + ch];
      acc.x += w[(ch+0)*4+k] * v.x;
      acc.y += w[(ch+1)*4+k] * v.y;
      acc.z += w[(ch+2)*4+k] * v.z;
      acc.w += w[(ch+3)*4+k] * v.w;
    }
  }
  float4 o; o.x=siluf(acc.x); o.y=siluf(acc.y); o.z=siluf(acc.z); o.w=siluf(acc.w);
  *(float4*)&xBC[(size_t)row*CONV_DIM + ch] = o;
}

// G[b,c][l][s] = sum_n C[l,n] * B[s,n]
__global__ __launch_bounds__(256) void g_kernel(const float* __restrict__ xBC, float* __restrict__ G) {
  int blk = blockIdx.x;                             // b*32 + c
  int b = blk >> 5, c = blk & 31;
  __shared__ float Bsh[64][129];
  int t = threadIdx.x;
  int row0 = b*LSEQ + c*CHUNK;
  for (int j=0;j<32;++j){
    int lin = j*256 + t;
    int s = lin >> 7, n = lin & 127;
    Bsh[s][n] = xBC[(size_t)(row0+s)*CONV_DIM + D_INNER + n];
  }
  __syncthreads();
  int l = t >> 2, s0 = (t & 3) * 16;
  const float* Cp = &xBC[(size_t)(row0+l)*CONV_DIM + D_INNER + D_STATE];
  float acc[16] = {};
  for (int n=0;n<128;++n){
    float cv = Cp[n];
    #pragma unroll
    for (int j=0;j<16;++j) acc[j] += cv * Bsh[s0+j][n];
  }
  float* Gp = &G[(size_t)blk*4096 + l*64 + s0];
  #pragma unroll
  for (int j=0;j<16;++j) Gp[j] = acc[j];
}

// ---------- MFMA states ----------
__global__ __launch_bounds__(256) void states_mfma(const float* __restrict__ xBC,
    const float* __restrict__ dt, const float* __restrict__ A_cum, float* __restrict__ states) {
  int blk = blockIdx.x;                             // (b*32+c)*32+h
  int h = blk & 31, c = (blk>>5)&31, b = blk>>10;
  __shared__ _Float16 Bt[128][72];                  // [n][s]
  __shared__ _Float16 xdT[64][72];                  // [p][s]
  __shared__ float Ac[64], dtl[64];
  int t = threadIdx.x;
  int wid = t >> 6, ln = t & 63;
  int row0 = b*LSEQ + c*CHUNK;
  if (t < 64){ Ac[t] = A_cum[((b*32+h)*32 + c)*64 + t]; dtl[t] = dt[(row0+t)*NHEADS + h]; }
  __syncthreads();
  float AcL = Ac[63];
  #pragma unroll
  for (int j=0;j<32;++j){
    int lin = j*256+t; int s = lin>>7, n = lin&127;
    Bt[n][s] = (_Float16)xBC[(size_t)(row0+s)*CONV_DIM + D_INNER + n];
  }
  #pragma unroll
  for (int j=0;j<16;++j){
    int lin = j*256+t; int s = lin>>6, p = lin&63;
    xdT[p][s] = (_Float16)(xBC[(size_t)(row0+s)*CONV_DIM + h*HEADDIM + p] * dtl[s] * expf(AcL - Ac[s]));
  }
  __syncthreads();
  const int fr = ln & 15, fk = (ln >> 4) * 8;
  f32x4 acc[4][2] = {};
  #pragma unroll
  for (int ks = 0; ks < 2; ++ks){
    half8 a[4], bb[2];
    #pragma unroll
    for (int pt=0;pt<4;++pt) a[pt] = *(const half8*)&xdT[pt*16+fr][ks*32+fk];
    #pragma unroll
    for (int nt=0;nt<2;++nt) bb[nt] = *(const half8*)&Bt[(wid*2+nt)*16+fr][ks*32+fk];
    #pragma unroll
    for (int pt=0;pt<4;++pt)
      #pragma unroll
      for (int nt=0;nt<2;++nt)
        acc[pt][nt] = __builtin_amdgcn_mfma_f32_16x16x32_f16(a[pt], bb[nt], acc[pt][nt], 0, 0, 0);
  }
  float* Sp = &states[(size_t)blk*8192];
  #pragma unroll
  for (int pt=0;pt<4;++pt){
    int p0 = pt*16 + (ln>>4)*4;
    #pragma unroll
    for (int nt=0;nt<2;++nt){
      int n = (wid*2+nt)*16 + fr;
      #pragma unroll
      for (int j=0;j<4;++j) Sp[(p0+j)*128 + n] = acc[pt][nt][j];
    }
  }
}

// inter-chunk scan, split 8-way over the 8192 state elements
__global__ __launch_bounds__(256) void scan_kernel(const float* __restrict__ A_cum,
                                                   float* __restrict__ states) {
  int g  = blockIdx.x & 7;
  int bh = blockIdx.x >> 3;                         // b*32+h
  int b = bh >> 5, h = bh & 31;
  int t = threadIdx.x;
  float S[4];
  #pragma unroll
  for (int j=0;j<4;++j) S[j] = 0.f;
  for (int c=0;c<NCHUNK;++c){
    float decay = expf(A_cum[((b*32+h)*32 + c)*64 + 63]);
    float* Sp = &states[(size_t)((b*32+c)*32 + h)*8192];
    #pragma unroll
    for (int j=0;j<4;++j){
      float tmp = Sp[(g*4+j)*256+t];
      Sp[(g*4+j)*256+t] = S[j];
      S[j] = S[j]*decay + tmp;
    }
  }
}

// ---------- MFMA Y ----------
__global__ __launch_bounds__(256) void y_mfma(const float* __restrict__ xBC,
    const float* __restrict__ zxbcdt, const float* __restrict__ dt,
    const float* __restrict__ A_cum, const float* __restrict__ G,
    const float* __restrict__ states, const float* __restrict__ Dp,
    float* __restrict__ y_pre) {
  int blk = blockIdx.x;                             // (b*32+c)*32+h
  int h = blk & 31, c = (blk>>5)&31, b = blk>>10;
  __shared__ _Float16 Cl[64][136];
  __shared__ _Float16 Sin[64][136];
  __shared__ _Float16 Ms[64][72];
  __shared__ _Float16 xdT[64][72];
  __shared__ float Ac[64], dtl[64];
  int t = threadIdx.x;
  int wid = t >> 6, ln = t & 63;
  int row0 = b*LSEQ + c*CHUNK;
  if (t < 64){ Ac[t] = A_cum[((b*32+h)*32 + c)*64 + t]; dtl[t] = dt[(row0+t)*NHEADS + h]; }
  __syncthreads();
  #pragma unroll
  for (int j=0;j<32;++j){
    int lin = j*256+t; int l = lin>>7, n = lin&127;
    Cl[l][n] = (_Float16)(xBC[(size_t)(row0+l)*CONV_DIM + D_INNER + D_STATE + n] * expf(Ac[l]));
  }
  {
    const float* Sg = &states[(size_t)blk*8192];
    #pragma unroll
    for (int j=0;j<32;++j){
      int lin = j*256+t; int p = lin>>7, n = lin&127;
      Sin[p][n] = (_Float16)Sg[lin];
    }
  }
  #pragma unroll
  for (int j=0;j<16;++j){
    int lin = j*256+t; int s = lin>>6, p = lin&63;
    xdT[p][s] = (_Float16)(xBC[(size_t)(row0+s)*CONV_DIM + h*HEADDIM + p] * dtl[s]);
  }
  {
    const float* Gp = &G[(size_t)(b*32+c)*4096];
    #pragma unroll
    for (int j=0;j<16;++j){
      int lin = j*256+t; int l = lin>>6, s = lin&63;
      Ms[l][s] = (s <= l) ? (_Float16)(Gp[l*64+s] * expf(Ac[l]-Ac[s])) : (_Float16)0.f;
    }
  }
  __syncthreads();
  const int wr = wid >> 1, wc = wid & 1;
  const int fr = ln & 15, fk = (ln >> 4) * 8;
  f32x4 acc[2][2] = {};
  #pragma unroll
  for (int ks = 0; ks < 4; ++ks){
    half8 a[2], bb[2];
    #pragma unroll
    for (int lt=0;lt<2;++lt) a[lt] = *(const half8*)&Cl[(wr*2+lt)*16+fr][ks*32+fk];
    #pragma unroll
    for (int pt=0;pt<2;++pt) bb[pt] = *(const half8*)&Sin[(wc*2+pt)*16+fr][ks*32+fk];
    #pragma unroll
    for (int lt=0;lt<2;++lt)
      #pragma unroll
      for (int pt=0;pt<2;++pt)
        acc[lt][pt] = __builtin_amdgcn_mfma_f32_16x16x32_f16(a[lt], bb[pt], acc[lt][pt], 0, 0, 0);
  }
  #pragma unroll
  for (int ks = 0; ks < 2; ++ks){
    half8 a[2], bb[2];
    #pragma unroll
    for (int lt=0;lt<2;++lt) a[lt] = *(const half8*)&Ms[(wr*2+lt)*16+fr][ks*32+fk];
    #pragma unroll
    for (int pt=0;pt<2;++pt) bb[pt] = *(const half8*)&xdT[(wc*2+pt)*16+fr][ks*32+fk];
    #pragma unroll
    for (int lt=0;lt<2;++lt)
      #pragma unroll
      for (int pt=0;pt<2;++pt)
        acc[lt][pt] = __builtin_amdgcn_mfma_f32_16x16x32_f16(a[lt], bb[pt], acc[lt][pt], 0, 0, 0);
  }
  float Dh = Dp[h];
  #pragma unroll
  for (int lt=0;lt<2;++lt){
    int l0 = (wr*2+lt)*16 + (ln>>4)*4;
    #pragma unroll
    for (int pt=0;pt<2;++pt){
      int p = (wc*2+pt)*16 + fr;
      #pragma unroll
      for (int j=0;j<4;++j){
        int grow = row0 + l0 + j;
        float x = xBC[(size_t)grow*CONV_DIM + h*HEADDIM + p];
        float z = zxbcdt[(size_t)grow*DPROJ + h*HEADDIM + p];
        y_pre[(size_t)grow*D_INNER + h*HEADDIM + p] = (acc[lt][pt][j] + x*Dh) * siluf(z);
      }
    }
  }
}

// RMS norm * norm_w, writes fp16 for GEMM2
__global__ __launch_bounds__(256) void rms_kernel(const float* __restrict__ y,
    const float* __restrict__ norm_w, unsigned short* __restrict__ yh) {
  int row = blockIdx.x;
  int t = threadIdx.x;
  float v[8];
  float ss = 0.f;
  const float* yr = &y[(size_t)row*D_INNER];
  #pragma unroll
  for (int j=0;j<8;++j){ v[j] = yr[j*256+t]; ss += v[j]*v[j]; }
  #pragma unroll
  for (int off=32; off>0; off>>=1) ss += __shfl_down(ss, off, 64);
  __shared__ float wsum[4];
  int wid = t >> 6, lane = t & 63;
  if (lane == 0) wsum[wid] = ss;
  __syncthreads();
  if (t == 0) wsum[0] = rsqrtf((wsum[0]+wsum[1]+wsum[2]+wsum[3])/D_INNER + EPSF);
  __syncthreads();
  float sc = wsum[0];
  #pragma unroll
  for (int j=0;j<8;++j) yh[(size_t)row*D_INNER + j*256+t] = f2h(v[j]*sc*norm_w[j*256+t]);
}

extern "C" void kernel_launch(void* const* d_in, const int* in_sizes, int n_in,
                              void* d_out, int out_size, void* d_ws, size_t ws_size,
                              hipStream_t stream) {
  const float* u       = (const float*)d_in[0];
  const float* W_in    = (const float*)d_in[1];
  const float* conv_w  = (const float*)d_in[2];
  const float* conv_b  = (const float*)d_in[3];
  const float* dt_bias = (const float*)d_in[4];
  const float* A_log   = (const float*)d_in[5];
  const float* Dp      = (const float*)d_in[6];
  const float* norm_w  = (const float*)d_in[7];
  const float* W_out   = (const float*)d_in[8];
  float* out = (float*)d_out;

  char* w = (char*)d_ws;
  float* zxbcdt = (float*)w;  w += (size_t)BL*DPROJ*4;                  // 71.8 MB
  float* xBC    = (float*)w;  w += (size_t)BL*CONV_DIM*4;               // 37.7 MB
  float* dt     = (float*)w;  w += (size_t)BL*NHEADS*4;
  float* A_cum  = (float*)w;  w += (size_t)B_SZ*NHEADS*NCHUNK*CHUNK*4;
  float* G      = (float*)w;  w += (size_t)B_SZ*NCHUNK*CHUNK*CHUNK*4;
  float* states = (float*)w;  w += (size_t)B_SZ*NCHUNK*NHEADS*HEADDIM*D_STATE*4; // 67.1 MB
  float* y_pre  = (float*)w;  w += (size_t)BL*D_INNER*4;                // 33.6 MB

  // time-aliased fp16 staging:
  unsigned short* u_h   = (unsigned short*)y_pre;                       // in y_pre region
  unsigned short* Win_h = u_h + (size_t)BL*D_MODEL;
  unsigned short* y_h    = (unsigned short*)zxbcdt;                     // in zxbcdt region
  unsigned short* Wout_h = y_h + (size_t)BL*D_INNER;

  cvt_f16<<<(BL*D_MODEL/4)/256, 256, 0, stream>>>(u, u_h, BL*D_MODEL/4);
  cvt_pad<<<((NPAD1*D_MODEL/4)+255)/256, 256, 0, stream>>>(W_in, Win_h, DPROJ, NPAD1*D_MODEL/4, D_MODEL/4);
  // 1) zxbcdt = u @ W_in.T   (fp16 MFMA, pipelined)
  gemm_f16_pipe<<<dim3(NPAD1/128, BL/128), 256, 0, stream>>>(u_h, Win_h, zxbcdt, DPROJ, D_MODEL);
  // 2) dt exact in fp32
  dt_gemm<<<BL/8, 256, 0, stream>>>(u, W_in, dt_bias, dt);
  // 3) per-chunk cumsum of A*dt
  acum_kernel<<<B_SZ*NHEADS*NCHUNK, 64, 0, stream>>>(dt, A_log, A_cum);
  // 4) depthwise conv + silu (float4)
  conv4_kernel<<<(BL*(CONV_DIM/4)+255)/256, 256, 0, stream>>>(zxbcdt, conv_w, conv_b, xBC);
  // 5) G = C B^T per (b,c)
  g_kernel<<<B_SZ*NCHUNK, 256, 0, stream>>>(xBC, G);
  // 6) per-chunk states (MFMA)
  states_mfma<<<B_SZ*NCHUNK*NHEADS, 256, 0, stream>>>(xBC, dt, A_cum, states);
  // 7) inter-chunk scan (in place -> states_in), 8-way split
  scan_kernel<<<B_SZ*NHEADS*8, 256, 0, stream>>>(A_cum, states);
  // 8) Y_diag + Y_off + D-term, gate with silu(z) (MFMA)
  y_mfma<<<B_SZ*NCHUNK*NHEADS, 256, 0, stream>>>(xBC, zxbcdt, dt, A_cum, G, states, Dp, y_pre);
  // convert W_out AFTER y_mfma (Wout_h aliases zxbcdt, now dead)
  cvt_f16<<<(D_MODEL*D_INNER/4)/256, 256, 0, stream>>>(W_out, Wout_h, D_MODEL*D_INNER/4);
  // 9) RMS norm -> fp16 (y_h aliases zxbcdt, dead)
  rms_kernel<<<BL, 256, 0, stream>>>(y_pre, norm_w, y_h);
  // 10) out = y @ W_out.T  (fp16 MFMA, pipelined)
  gemm_f16_pipe<<<dim3(D_MODEL/128, BL/128), 256, 0, stream>>>(y_h, Wout_h, out, D_MODEL, D_INNER);
}

// Round 7
// 285.578 us; speedup vs baseline: 5.2524x; 1.2238x over previous
//
#include <hip/hip_runtime.h>
#include <hip/hip_bf16.h>
#include <math.h>

#define D_MODEL 1024
#define D_INNER 2048
#define D_STATE 128
#define NHEADS 32
#define HEADDIM 64
#define CHUNK 64
#define B_SZ 2
#define LSEQ 2048
#define BL (B_SZ*LSEQ)                              // 4096
#define DPROJ (2*D_INNER + 2*D_STATE + NHEADS)      // 4384
#define CONV_DIM (D_INNER + 2*D_STATE)              // 2304
#define NCHUNK (LSEQ/CHUNK)                         // 32
#define NPAD1 4480                                  // DPROJ padded to x128
#define EPSF 1e-5f

typedef __attribute__((ext_vector_type(8))) _Float16 half8;
typedef __attribute__((ext_vector_type(4))) float f32x4;

__device__ __forceinline__ float siluf(float v){ return v / (1.0f + expf(-v)); }
__device__ __forceinline__ float softplusf(float v){ return v > 20.0f ? v : log1pf(expf(v)); }
__device__ __forceinline__ unsigned short f2h(float x){
  _Float16 h = (_Float16)x;
  union { _Float16 h; unsigned short u; } v; v.h = h;
  return v.u;
}

typedef const __attribute__((address_space(1))) void gvoid_t;
typedef __attribute__((address_space(3))) void lvoid_t;
__device__ __forceinline__ void gl_lds16(const void* gsrc, void* ldst) {
  gvoid_t* g = reinterpret_cast<gvoid_t*>((uintptr_t)gsrc);
  lvoid_t* l = reinterpret_cast<lvoid_t*>((unsigned int)(uintptr_t)ldst);
  __builtin_amdgcn_global_load_lds(g, l, 16, 0, 0);
}

// ---------- fp32 -> fp16 converters ----------
__global__ void cvt_f16(const float* __restrict__ in, unsigned short* __restrict__ out, int n4) {
  int i = blockIdx.x*256 + threadIdx.x;
  if (i >= n4) return;
  float4 v = *(const float4*)(in + (size_t)i*4);
  ushort4 o; o.x=f2h(v.x); o.y=f2h(v.y); o.z=f2h(v.z); o.w=f2h(v.w);
  *(ushort4*)(out + (size_t)i*4) = o;
}

__global__ void cvt_pad(const float* __restrict__ in, unsigned short* __restrict__ out,
                        int rows_in, int total4, int kdim4) {
  int i = blockIdx.x*256 + threadIdx.x;
  if (i >= total4) return;
  int row = i / kdim4;
  ushort4 o; o.x=0; o.y=0; o.z=0; o.w=0;
  if (row < rows_in) {
    float4 v = *(const float4*)(in + (size_t)i*4);
    o.x=f2h(v.x); o.y=f2h(v.y); o.z=f2h(v.z); o.w=f2h(v.w);
  }
  *(ushort4*)(out + (size_t)i*4) = o;
}

// ---------- pipelined fp16 MFMA GEMM ----------
__global__ __launch_bounds__(256) void gemm_f16_pipe(const unsigned short* __restrict__ A,
    const unsigned short* __restrict__ W, float* __restrict__ C, int N, int K) {
  __shared__ unsigned short lds[3*2*4096];          // 48 KB
  const int t   = threadIdx.x;
  const int wid = t >> 6, l = t & 63;
  const int nwg = gridDim.x * gridDim.y;
  int bid = blockIdx.y * gridDim.x + blockIdx.x;
  int swz = (bid & 7) * (nwg >> 3) + (bid >> 3);    // XCD-chunked (nwg%8==0)
  const int m0 = (swz / gridDim.x) * 128;
  const int n0 = (swz % gridDim.x) * 128;
  const int wr = wid >> 1, wc = wid & 1;
  const int fr = l & 15, cg = l >> 4;
  const int NT = K >> 5;

  int srow[2]; int scol[2];
  #pragma unroll
  for (int i=0;i<2;++i){
    int s = i*256 + t;
    int r = s >> 2, c = s & 3;
    int sw = (r + (r>>2)) & 3;
    srow[i] = r; scol[i] = (c ^ sw) * 8;
  }
  const unsigned short* Abase = A + (size_t)m0 * K;
  const unsigned short* Wbase = W + (size_t)n0 * K;

#define STAGE(tt, slot) { \
    int kk = (tt) << 5; \
    unsigned short* La = &lds[(slot)*8192]; \
    unsigned short* Lb = &lds[(slot)*8192 + 4096]; \
    gl_lds16(Abase + (size_t)srow[0]*K + kk + scol[0], (char*)La + (0*256+t)*16); \
    gl_lds16(Abase + (size_t)srow[1]*K + kk + scol[1], (char*)La + (1*256+t)*16); \
    gl_lds16(Wbase + (size_t)srow[0]*K + kk + scol[0], (char*)Lb + (0*256+t)*16); \
    gl_lds16(Wbase + (size_t)srow[1]*K + kk + scol[1], (char*)Lb + (1*256+t)*16); \
  }

  f32x4 acc[4][4] = {};
  STAGE(0, 0);
  STAGE(1, 1);
  asm volatile("s_waitcnt vmcnt(4)" ::: "memory");
  __builtin_amdgcn_s_barrier();
  asm volatile("" ::: "memory");

  for (int tt = 0; tt < NT; ++tt) {
    int slot = tt % 3;
    if (tt + 2 < NT) STAGE(tt+2, (tt+2)%3);
    const unsigned short* La = &lds[slot*8192];
    const unsigned short* Lb = &lds[slot*8192 + 4096];
    half8 af[4], bfv[4];
    #pragma unroll
    for (int m=0;m<4;++m){
      int r = wr*64 + m*16 + fr;
      int sw = (r + (r>>2)) & 3;
      af[m] = *(const half8*)&La[(r*4 + (cg ^ sw))*8];
    }
    #pragma unroll
    for (int n=0;n<4;++n){
      int r = wc*64 + n*16 + fr;
      int sw = (r + (r>>2)) & 3;
      bfv[n] = *(const half8*)&Lb[(r*4 + (cg ^ sw))*8];
    }
    __builtin_amdgcn_s_setprio(1);
    #pragma unroll
    for (int m=0;m<4;++m)
      #pragma unroll
      for (int n=0;n<4;++n)
        acc[m][n] = __builtin_amdgcn_mfma_f32_16x16x32_f16(af[m], bfv[n], acc[m][n], 0, 0, 0);
    __builtin_amdgcn_s_setprio(0);
    if (tt + 2 < NT) { asm volatile("s_waitcnt vmcnt(4)" ::: "memory"); }
    else             { asm volatile("s_waitcnt vmcnt(0)" ::: "memory"); }
    __builtin_amdgcn_s_barrier();
    asm volatile("" ::: "memory");
  }
#undef STAGE

  const int crow = m0 + wr*64 + (l >> 4) * 4;
  const int ccol0 = n0 + wc*64 + fr;
  #pragma unroll
  for (int m = 0; m < 4; ++m) {
    #pragma unroll
    for (int n = 0; n < 4; ++n) {
      int col = ccol0 + n*16;
      if (col < N) {
        float* cp = C + (size_t)(crow + m*16)*N + col;
        #pragma unroll
        for (int j = 0; j < 4; ++j) cp[(size_t)j*N] = acc[m][n][j];
      }
    }
  }
}

// ---------- exact fp32 dt path ----------
__global__ __launch_bounds__(256) void dt_gemm(const float* __restrict__ u,
    const float* __restrict__ W_in, const float* __restrict__ dt_bias, float* __restrict__ dt) {
  __shared__ float Wsh[32][129];
  __shared__ float Ush[8][129];
  int t = threadIdx.x;
  int row0 = blockIdx.x * 8;
  int h = t & 31, rs = t >> 5;
  float acc = 0.f;
  for (int k0 = 0; k0 < D_MODEL; k0 += 128) {
    #pragma unroll
    for (int j = 0; j < 16; ++j) {
      int lin = j*256 + t; int hh = lin >> 7, kk = lin & 127;
      Wsh[hh][kk] = W_in[(size_t)(2*D_INNER + 2*D_STATE + hh)*D_MODEL + k0 + kk];
    }
    #pragma unroll
    for (int j = 0; j < 4; ++j) {
      int lin = j*256 + t; int rr = lin >> 7, kk = lin & 127;
      Ush[rr][kk] = u[(size_t)(row0+rr)*D_MODEL + k0 + kk];
    }
    __syncthreads();
    #pragma unroll 4
    for (int k = 0; k < 128; ++k) acc += Ush[rs][k] * Wsh[h][k];
    __syncthreads();
  }
  dt[(row0+rs)*NHEADS + h] = softplusf(acc + dt_bias[h]);
}

// A_cum[(b*32+h)*32+c][l]
__global__ __launch_bounds__(64) void acum_kernel(const float* __restrict__ dt,
    const float* __restrict__ A_log, float* __restrict__ A_cum) {
  int blk = blockIdx.x;                             // (b*32+h)*32+c
  int c = blk & 31, h = (blk >> 5) & 31, b = blk >> 10;
  int l = threadIdx.x;
  __shared__ float sv[64];
  int row = b*LSEQ + c*CHUNK + l;
  float a = -expf(A_log[h]);
  sv[l] = a * dt[row*NHEADS + h];
  __syncthreads();
  if (l == 0) {
    float s = 0.f;
    for (int i=0;i<64;++i){ s += sv[i]; sv[i] = s; }
  }
  __syncthreads();
  A_cum[blk*64 + l] = sv[l];
}

// causal depthwise conv (K=4) + bias + silu; 8 rows x 4 channels per thread
__global__ __launch_bounds__(256) void conv8_kernel(const float* __restrict__ zxbcdt,
    const float* __restrict__ w, const float* __restrict__ bias, float* __restrict__ xBC) {
  int idx = blockIdx.x*256 + threadIdx.x;           // over (BL/8) * (CONV_DIM/4)
  if (idx >= (BL/8)*(CONV_DIM/4)) return;
  int c4  = idx % (CONV_DIM/4);
  int rb  = idx / (CONV_DIM/4);
  int ch  = c4 * 4;
  int row0 = rb * 8;
  int l0   = row0 & (LSEQ-1);
  float4 r[11];
  #pragma unroll
  for (int jj=0;jj<11;++jj){
    int li = l0 + jj - 3;
    if (li >= 0) r[jj] = *(const float4*)&zxbcdt[(size_t)(row0 + jj - 3)*DPROJ + D_INNER + ch];
    else         r[jj] = make_float4(0.f,0.f,0.f,0.f);
  }
  float4 wv[4];
  #pragma unroll
  for (int c=0;c<4;++c) wv[c] = *(const float4*)&w[(ch+c)*4];
  float4 bv = *(const float4*)&bias[ch];
  #pragma unroll
  for (int j=0;j<8;++j){
    float4 acc = bv;
    acc.x += wv[0].x*r[j].x + wv[0].y*r[j+1].x + wv[0].z*r[j+2].x + wv[0].w*r[j+3].x;
    acc.y += wv[1].x*r[j].y + wv[1].y*r[j+1].y + wv[1].z*r[j+2].y + wv[1].w*r[j+3].y;
    acc.z += wv[2].x*r[j].z + wv[2].y*r[j+1].z + wv[2].z*r[j+2].z + wv[2].w*r[j+3].z;
    acc.w += wv[3].x*r[j].w + wv[3].y*r[j+1].w + wv[3].z*r[j+2].w + wv[3].w*r[j+3].w;
    float4 o; o.x=siluf(acc.x); o.y=siluf(acc.y); o.z=siluf(acc.z); o.w=siluf(acc.w);
    *(float4*)&xBC[(size_t)(row0+j)*CONV_DIM + ch] = o;
  }
}

// G[b,c][l][s] = sum_n C[l,n] * B[s,n]; 4 blocks per (b,c), 16 l-rows each
__global__ __launch_bounds__(256) void g_kernel(const float* __restrict__ xBC, float* __restrict__ G) {
  int blk = blockIdx.x >> 2;                        // b*32 + c
  int lq  = blockIdx.x & 3;                         // l-quarter
  int b = blk >> 5, c = blk & 31;
  __shared__ float Bsh[64][129];
  int t = threadIdx.x;
  int row0 = b*LSEQ + c*CHUNK;
  for (int j=0;j<32;++j){
    int lin = j*256 + t;
    int s = lin >> 7, n = lin & 127;
    Bsh[s][n] = xBC[(size_t)(row0+s)*CONV_DIM + D_INNER + n];
  }
  __syncthreads();
  int l = lq*16 + (t >> 4), s0 = (t & 15) * 4;
  const float* Cp = &xBC[(size_t)(row0+l)*CONV_DIM + D_INNER + D_STATE];
  float acc[4] = {};
  for (int n=0;n<128;++n){
    float cv = Cp[n];
    #pragma unroll
    for (int j=0;j<4;++j) acc[j] += cv * Bsh[s0+j][n];
  }
  float* Gp = &G[(size_t)blk*4096 + l*64 + s0];
  #pragma unroll
  for (int j=0;j<4;++j) Gp[j] = acc[j];
}

// ---------- MFMA states ----------
__global__ __launch_bounds__(256) void states_mfma(const float* __restrict__ xBC,
    const float* __restrict__ dt, const float* __restrict__ A_cum, float* __restrict__ states) {
  int blk = blockIdx.x;                             // (b*32+c)*32+h
  int h = blk & 31, c = (blk>>5)&31, b = blk>>10;
  __shared__ _Float16 Bt[128][72];                  // [n][s]
  __shared__ _Float16 xdT[64][72];                  // [p][s]
  __shared__ float Ac[64], dtl[64];
  int t = threadIdx.x;
  int wid = t >> 6, ln = t & 63;
  int row0 = b*LSEQ + c*CHUNK;
  if (t < 64){ Ac[t] = A_cum[((b*32+h)*32 + c)*64 + t]; dtl[t] = dt[(row0+t)*NHEADS + h]; }
  __syncthreads();
  float AcL = Ac[63];
  #pragma unroll
  for (int j=0;j<32;++j){
    int lin = j*256+t; int s = lin>>7, n = lin&127;
    Bt[n][s] = (_Float16)xBC[(size_t)(row0+s)*CONV_DIM + D_INNER + n];
  }
  #pragma unroll
  for (int j=0;j<16;++j){
    int lin = j*256+t; int s = lin>>6, p = lin&63;
    xdT[p][s] = (_Float16)(xBC[(size_t)(row0+s)*CONV_DIM + h*HEADDIM + p] * dtl[s] * expf(AcL - Ac[s]));
  }
  __syncthreads();
  const int fr = ln & 15, fk = (ln >> 4) * 8;
  f32x4 acc[4][2] = {};
  #pragma unroll
  for (int ks = 0; ks < 2; ++ks){
    half8 a[4], bb[2];
    #pragma unroll
    for (int pt=0;pt<4;++pt) a[pt] = *(const half8*)&xdT[pt*16+fr][ks*32+fk];
    #pragma unroll
    for (int nt=0;nt<2;++nt) bb[nt] = *(const half8*)&Bt[(wid*2+nt)*16+fr][ks*32+fk];
    #pragma unroll
    for (int pt=0;pt<4;++pt)
      #pragma unroll
      for (int nt=0;nt<2;++nt)
        acc[pt][nt] = __builtin_amdgcn_mfma_f32_16x16x32_f16(a[pt], bb[nt], acc[pt][nt], 0, 0, 0);
  }
  float* Sp = &states[(size_t)blk*8192];
  #pragma unroll
  for (int pt=0;pt<4;++pt){
    int p0 = pt*16 + (ln>>4)*4;
    #pragma unroll
    for (int nt=0;nt<2;++nt){
      int n = (wid*2+nt)*16 + fr;
      #pragma unroll
      for (int j=0;j<4;++j) Sp[(p0+j)*128 + n] = acc[pt][nt][j];
    }
  }
}

// inter-chunk scan, split 8-way over the 8192 state elements
__global__ __launch_bounds__(256) void scan_kernel(const float* __restrict__ A_cum,
                                                   float* __restrict__ states) {
  int g  = blockIdx.x & 7;
  int bh = blockIdx.x >> 3;                         // b*32+h
  int b = bh >> 5, h = bh & 31;
  int t = threadIdx.x;
  float S[4];
  #pragma unroll
  for (int j=0;j<4;++j) S[j] = 0.f;
  for (int c=0;c<NCHUNK;++c){
    float decay = expf(A_cum[((b*32+h)*32 + c)*64 + 63]);
    float* Sp = &states[(size_t)((b*32+c)*32 + h)*8192];
    #pragma unroll
    for (int j=0;j<4;++j){
      float tmp = Sp[(g*4+j)*256+t];
      Sp[(g*4+j)*256+t] = S[j];
      S[j] = S[j]*decay + tmp;
    }
  }
}

// ---------- MFMA Y ----------
__global__ __launch_bounds__(256) void y_mfma(const float* __restrict__ xBC,
    const float* __restrict__ zxbcdt, const float* __restrict__ dt,
    const float* __restrict__ A_cum, const float* __restrict__ G,
    const float* __restrict__ states, const float* __restrict__ Dp,
    float* __restrict__ y_pre) {
  int blk = blockIdx.x;                             // (b*32+c)*32+h
  int h = blk & 31, c = (blk>>5)&31, b = blk>>10;
  __shared__ _Float16 Cl[64][136];
  __shared__ _Float16 Sin[64][136];
  __shared__ _Float16 Ms[64][72];
  __shared__ _Float16 xdT[64][72];
  __shared__ float Ac[64], dtl[64];
  int t = threadIdx.x;
  int wid = t >> 6, ln = t & 63;
  int row0 = b*LSEQ + c*CHUNK;
  if (t < 64){ Ac[t] = A_cum[((b*32+h)*32 + c)*64 + t]; dtl[t] = dt[(row0+t)*NHEADS + h]; }
  __syncthreads();
  #pragma unroll
  for (int j=0;j<32;++j){
    int lin = j*256+t; int l = lin>>7, n = lin&127;
    Cl[l][n] = (_Float16)(xBC[(size_t)(row0+l)*CONV_DIM + D_INNER + D_STATE + n] * expf(Ac[l]));
  }
  {
    const float* Sg = &states[(size_t)blk*8192];
    #pragma unroll
    for (int j=0;j<32;++j){
      int lin = j*256+t; int p = lin>>7, n = lin&127;
      Sin[p][n] = (_Float16)Sg[lin];
    }
  }
  #pragma unroll
  for (int j=0;j<16;++j){
    int lin = j*256+t; int s = lin>>6, p = lin&63;
    xdT[p][s] = (_Float16)(xBC[(size_t)(row0+s)*CONV_DIM + h*HEADDIM + p] * dtl[s]);
  }
  {
    const float* Gp = &G[(size_t)(b*32+c)*4096];
    #pragma unroll
    for (int j=0;j<16;++j){
      int lin = j*256+t; int l = lin>>6, s = lin&63;
      Ms[l][s] = (s <= l) ? (_Float16)(Gp[l*64+s] * expf(Ac[l]-Ac[s])) : (_Float16)0.f;
    }
  }
  __syncthreads();
  const int wr = wid >> 1, wc = wid & 1;
  const int fr = ln & 15, fk = (ln >> 4) * 8;
  f32x4 acc[2][2] = {};
  #pragma unroll
  for (int ks = 0; ks < 4; ++ks){
    half8 a[2], bb[2];
    #pragma unroll
    for (int lt=0;lt<2;++lt) a[lt] = *(const half8*)&Cl[(wr*2+lt)*16+fr][ks*32+fk];
    #pragma unroll
    for (int pt=0;pt<2;++pt) bb[pt] = *(const half8*)&Sin[(wc*2+pt)*16+fr][ks*32+fk];
    #pragma unroll
    for (int lt=0;lt<2;++lt)
      #pragma unroll
      for (int pt=0;pt<2;++pt)
        acc[lt][pt] = __builtin_amdgcn_mfma_f32_16x16x32_f16(a[lt], bb[pt], acc[lt][pt], 0, 0, 0);
  }
  #pragma unroll
  for (int ks = 0; ks < 2; ++ks){
    half8 a[2], bb[2];
    #pragma unroll
    for (int lt=0;lt<2;++lt) a[lt] = *(const half8*)&Ms[(wr*2+lt)*16+fr][ks*32+fk];
    #pragma unroll
    for (int pt=0;pt<2;++pt) bb[pt] = *(const half8*)&xdT[(wc*2+pt)*16+fr][ks*32+fk];
    #pragma unroll
    for (int lt=0;lt<2;++lt)
      #pragma unroll
      for (int pt=0;pt<2;++pt)
        acc[lt][pt] = __builtin_amdgcn_mfma_f32_16x16x32_f16(a[lt], bb[pt], acc[lt][pt], 0, 0, 0);
  }
  float Dh = Dp[h];
  #pragma unroll
  for (int lt=0;lt<2;++lt){
    int l0 = (wr*2+lt)*16 + (ln>>4)*4;
    #pragma unroll
    for (int pt=0;pt<2;++pt){
      int p = (wc*2+pt)*16 + fr;
      #pragma unroll
      for (int j=0;j<4;++j){
        int grow = row0 + l0 + j;
        float x = xBC[(size_t)grow*CONV_DIM + h*HEADDIM + p];
        float z = zxbcdt[(size_t)grow*DPROJ + h*HEADDIM + p];
        y_pre[(size_t)grow*D_INNER + h*HEADDIM + p] = (acc[lt][pt][j] + x*Dh) * siluf(z);
      }
    }
  }
}

// RMS norm * norm_w, writes fp16 for GEMM2
__global__ __launch_bounds__(256) void rms_kernel(const float* __restrict__ y,
    const float* __restrict__ norm_w, unsigned short* __restrict__ yh) {
  int row = blockIdx.x;
  int t = threadIdx.x;
  float v[8];
  float ss = 0.f;
  const float* yr = &y[(size_t)row*D_INNER];
  #pragma unroll
  for (int j=0;j<8;++j){ v[j] = yr[j*256+t]; ss += v[j]*v[j]; }
  #pragma unroll
  for (int off=32; off>0; off>>=1) ss += __shfl_down(ss, off, 64);
  __shared__ float wsum[4];
  int wid = t >> 6, lane = t & 63;
  if (lane == 0) wsum[wid] = ss;
  __syncthreads();
  if (t == 0) wsum[0] = rsqrtf((wsum[0]+wsum[1]+wsum[2]+wsum[3])/D_INNER + EPSF);
  __syncthreads();
  float sc = wsum[0];
  #pragma unroll
  for (int j=0;j<8;++j) yh[(size_t)row*D_INNER + j*256+t] = f2h(v[j]*sc*norm_w[j*256+t]);
}

extern "C" void kernel_launch(void* const* d_in, const int* in_sizes, int n_in,
                              void* d_out, int out_size, void* d_ws, size_t ws_size,
                              hipStream_t stream) {
  const float* u       = (const float*)d_in[0];
  const float* W_in    = (const float*)d_in[1];
  const float* conv_w  = (const float*)d_in[2];
  const float* conv_b  = (const float*)d_in[3];
  const float* dt_bias = (const float*)d_in[4];
  const float* A_log   = (const float*)d_in[5];
  const float* Dp      = (const float*)d_in[6];
  const float* norm_w  = (const float*)d_in[7];
  const float* W_out   = (const float*)d_in[8];
  float* out = (float*)d_out;

  char* w = (char*)d_ws;
  float* zxbcdt = (float*)w;  w += (size_t)BL*DPROJ*4;                  // 71.8 MB
  float* xBC    = (float*)w;  w += (size_t)BL*CONV_DIM*4;               // 37.7 MB
  float* dt     = (float*)w;  w += (size_t)BL*NHEADS*4;
  float* A_cum  = (float*)w;  w += (size_t)B_SZ*NHEADS*NCHUNK*CHUNK*4;
  float* G      = (float*)w;  w += (size_t)B_SZ*NCHUNK*CHUNK*CHUNK*4;
  float* states = (float*)w;  w += (size_t)B_SZ*NCHUNK*NHEADS*HEADDIM*D_STATE*4; // 67.1 MB
  float* y_pre  = (float*)w;  w += (size_t)BL*D_INNER*4;                // 33.6 MB

  unsigned short* u_h   = (unsigned short*)y_pre;                       // in y_pre region
  unsigned short* Win_h = u_h + (size_t)BL*D_MODEL;
  unsigned short* y_h    = (unsigned short*)zxbcdt;                     // in zxbcdt region
  unsigned short* Wout_h = y_h + (size_t)BL*D_INNER;

  cvt_f16<<<(BL*D_MODEL/4)/256, 256, 0, stream>>>(u, u_h, BL*D_MODEL/4);
  cvt_pad<<<((NPAD1*D_MODEL/4)+255)/256, 256, 0, stream>>>(W_in, Win_h, DPROJ, NPAD1*D_MODEL/4, D_MODEL/4);
  // 1) zxbcdt = u @ W_in.T
  gemm_f16_pipe<<<dim3(NPAD1/128, BL/128), 256, 0, stream>>>(u_h, Win_h, zxbcdt, DPROJ, D_MODEL);
  // 2) dt exact in fp32
  dt_gemm<<<BL/8, 256, 0, stream>>>(u, W_in, dt_bias, dt);
  // 3) per-chunk cumsum of A*dt
  acum_kernel<<<B_SZ*NHEADS*NCHUNK, 64, 0, stream>>>(dt, A_log, A_cum);
  // 4) depthwise conv + silu (8 rows/thread)
  conv8_kernel<<<((BL/8)*(CONV_DIM/4)+255)/256, 256, 0, stream>>>(zxbcdt, conv_w, conv_b, xBC);
  // 5) G = C B^T per (b,c), 4-way split over l
  g_kernel<<<B_SZ*NCHUNK*4, 256, 0, stream>>>(xBC, G);
  // 6) per-chunk states (MFMA)
  states_mfma<<<B_SZ*NCHUNK*NHEADS, 256, 0, stream>>>(xBC, dt, A_cum, states);
  // 7) inter-chunk scan, 8-way split
  scan_kernel<<<B_SZ*NHEADS*8, 256, 0, stream>>>(A_cum, states);
  // 8) Y (MFMA)
  y_mfma<<<B_SZ*NCHUNK*NHEADS, 256, 0, stream>>>(xBC, zxbcdt, dt, A_cum, G, states, Dp, y_pre);
  // convert W_out AFTER y_mfma (aliases zxbcdt)
  cvt_f16<<<(D_MODEL*D_INNER/4)/256, 256, 0, stream>>>(W_out, Wout_h, D_MODEL*D_INNER/4);
  // 9) RMS norm -> fp16
  rms_kernel<<<BL, 256, 0, stream>>>(y_pre, norm_w, y_h);
  // 10) out = y @ W_out.T
  gemm_f16_pipe<<<dim3(D_MODEL/128, BL/128), 256, 0, stream>>>(y_h, Wout_h, out, D_MODEL, D_INNER);
}

// Round 8
// 271.334 us; speedup vs baseline: 5.5281x; 1.0525x over previous
//
#include <hip/hip_runtime.h>
#include <hip/hip_bf16.h>
#include <math.h>

#define D_MODEL 1024
#define D_INNER 2048
#define D_STATE 128
#define NHEADS 32
#define HEADDIM 64
#define CHUNK 64
#define B_SZ 2
#define LSEQ 2048
#define BL (B_SZ*LSEQ)                              // 4096
#define DPROJ (2*D_INNER + 2*D_STATE + NHEADS)      // 4384
#define CONV_DIM (D_INNER + 2*D_STATE)              // 2304
#define NCHUNK (LSEQ/CHUNK)                         // 32
#define NPAD1 4480                                  // DPROJ padded to x128
#define EPSF 1e-5f

typedef __attribute__((ext_vector_type(8))) _Float16 half8;
typedef __attribute__((ext_vector_type(4))) float f32x4;

__device__ __forceinline__ float siluf(float v){ return v / (1.0f + expf(-v)); }
__device__ __forceinline__ float softplusf(float v){ return v > 20.0f ? v : log1pf(expf(v)); }
__device__ __forceinline__ unsigned short f2h(float x){
  union { _Float16 h; unsigned short u; } v; v.h = (_Float16)x;
  return v.u;
}
__device__ __forceinline__ float h2f(unsigned short x){
  union { unsigned short u; _Float16 h; } v; v.u = x;
  return (float)v.h;
}
__device__ __forceinline__ _Float16 h2h(unsigned short x){
  union { unsigned short u; _Float16 h; } v; v.u = x;
  return v.h;
}

typedef const __attribute__((address_space(1))) void gvoid_t;
typedef __attribute__((address_space(3))) void lvoid_t;
__device__ __forceinline__ void gl_lds16(const void* gsrc, void* ldst) {
  gvoid_t* g = reinterpret_cast<gvoid_t*>((uintptr_t)gsrc);
  lvoid_t* l = reinterpret_cast<lvoid_t*>((unsigned int)(uintptr_t)ldst);
  __builtin_amdgcn_global_load_lds(g, l, 16, 0, 0);
}

// ---------- fp32 -> fp16 converters ----------
__global__ void cvt_f16(const float* __restrict__ in, unsigned short* __restrict__ out, int n4) {
  int i = blockIdx.x*256 + threadIdx.x;
  if (i >= n4) return;
  float4 v = *(const float4*)(in + (size_t)i*4);
  ushort4 o; o.x=f2h(v.x); o.y=f2h(v.y); o.z=f2h(v.z); o.w=f2h(v.w);
  *(ushort4*)(out + (size_t)i*4) = o;
}

__global__ void cvt_pad(const float* __restrict__ in, unsigned short* __restrict__ out,
                        int rows_in, int total4, int kdim4) {
  int i = blockIdx.x*256 + threadIdx.x;
  if (i >= total4) return;
  int row = i / kdim4;
  ushort4 o; o.x=0; o.y=0; o.z=0; o.w=0;
  if (row < rows_in) {
    float4 v = *(const float4*)(in + (size_t)i*4);
    o.x=f2h(v.x); o.y=f2h(v.y); o.z=f2h(v.z); o.w=f2h(v.w);
  }
  *(ushort4*)(out + (size_t)i*4) = o;
}

// ---------- pipelined fp16 MFMA GEMM; OUT_F16 selects fp16 or fp32 C ----------
template<int OUT_F16>
__global__ __launch_bounds__(256) void gemm_f16_pipe(const unsigned short* __restrict__ A,
    const unsigned short* __restrict__ W, void* __restrict__ Cv, int N, int K) {
  __shared__ unsigned short lds[3*2*4096];          // 48 KB
  const int t   = threadIdx.x;
  const int wid = t >> 6, l = t & 63;
  const int nwg = gridDim.x * gridDim.y;
  int bid = blockIdx.y * gridDim.x + blockIdx.x;
  int swz = (bid & 7) * (nwg >> 3) + (bid >> 3);    // XCD-chunked (nwg%8==0)
  const int m0 = (swz / gridDim.x) * 128;
  const int n0 = (swz % gridDim.x) * 128;
  const int wr = wid >> 1, wc = wid & 1;
  const int fr = l & 15, cg = l >> 4;
  const int NT = K >> 5;

  int srow[2]; int scol[2];
  #pragma unroll
  for (int i=0;i<2;++i){
    int s = i*256 + t;
    int r = s >> 2, c = s & 3;
    int sw = (r + (r>>2)) & 3;
    srow[i] = r; scol[i] = (c ^ sw) * 8;
  }
  const unsigned short* Abase = A + (size_t)m0 * K;
  const unsigned short* Wbase = W + (size_t)n0 * K;

#define STAGE(tt, slot) { \
    int kk = (tt) << 5; \
    unsigned short* La = &lds[(slot)*8192]; \
    unsigned short* Lb = &lds[(slot)*8192 + 4096]; \
    gl_lds16(Abase + (size_t)srow[0]*K + kk + scol[0], (char*)La + (0*256+t)*16); \
    gl_lds16(Abase + (size_t)srow[1]*K + kk + scol[1], (char*)La + (1*256+t)*16); \
    gl_lds16(Wbase + (size_t)srow[0]*K + kk + scol[0], (char*)Lb + (0*256+t)*16); \
    gl_lds16(Wbase + (size_t)srow[1]*K + kk + scol[1], (char*)Lb + (1*256+t)*16); \
  }

  f32x4 acc[4][4] = {};
  STAGE(0, 0);
  STAGE(1, 1);
  asm volatile("s_waitcnt vmcnt(4)" ::: "memory");
  __builtin_amdgcn_s_barrier();
  asm volatile("" ::: "memory");

  for (int tt = 0; tt < NT; ++tt) {
    int slot = tt % 3;
    if (tt + 2 < NT) STAGE(tt+2, (tt+2)%3);
    const unsigned short* La = &lds[slot*8192];
    const unsigned short* Lb = &lds[slot*8192 + 4096];
    half8 af[4], bfv[4];
    #pragma unroll
    for (int m=0;m<4;++m){
      int r = wr*64 + m*16 + fr;
      int sw = (r + (r>>2)) & 3;
      af[m] = *(const half8*)&La[(r*4 + (cg ^ sw))*8];
    }
    #pragma unroll
    for (int n=0;n<4;++n){
      int r = wc*64 + n*16 + fr;
      int sw = (r + (r>>2)) & 3;
      bfv[n] = *(const half8*)&Lb[(r*4 + (cg ^ sw))*8];
    }
    __builtin_amdgcn_s_setprio(1);
    #pragma unroll
    for (int m=0;m<4;++m)
      #pragma unroll
      for (int n=0;n<4;++n)
        acc[m][n] = __builtin_amdgcn_mfma_f32_16x16x32_f16(af[m], bfv[n], acc[m][n], 0, 0, 0);
    __builtin_amdgcn_s_setprio(0);
    if (tt + 2 < NT) { asm volatile("s_waitcnt vmcnt(4)" ::: "memory"); }
    else             { asm volatile("s_waitcnt vmcnt(0)" ::: "memory"); }
    __builtin_amdgcn_s_barrier();
    asm volatile("" ::: "memory");
  }
#undef STAGE

  const int crow = m0 + wr*64 + (l >> 4) * 4;
  const int ccol0 = n0 + wc*64 + fr;
  #pragma unroll
  for (int m = 0; m < 4; ++m) {
    #pragma unroll
    for (int n = 0; n < 4; ++n) {
      int col = ccol0 + n*16;
      if (col < N) {
        if (OUT_F16) {
          unsigned short* cp = (unsigned short*)Cv + (size_t)(crow + m*16)*N + col;
          #pragma unroll
          for (int j = 0; j < 4; ++j) cp[(size_t)j*N] = f2h(acc[m][n][j]);
        } else {
          float* cp = (float*)Cv + (size_t)(crow + m*16)*N + col;
          #pragma unroll
          for (int j = 0; j < 4; ++j) cp[(size_t)j*N] = acc[m][n][j];
        }
      }
    }
  }
}

// ---------- exact fp32 dt path ----------
__global__ __launch_bounds__(256) void dt_gemm(const float* __restrict__ u,
    const float* __restrict__ W_in, const float* __restrict__ dt_bias, float* __restrict__ dt) {
  __shared__ float Wsh[32][129];
  __shared__ float Ush[8][129];
  int t = threadIdx.x;
  int row0 = blockIdx.x * 8;
  int h = t & 31, rs = t >> 5;
  float acc = 0.f;
  for (int k0 = 0; k0 < D_MODEL; k0 += 128) {
    #pragma unroll
    for (int j = 0; j < 16; ++j) {
      int lin = j*256 + t; int hh = lin >> 7, kk = lin & 127;
      Wsh[hh][kk] = W_in[(size_t)(2*D_INNER + 2*D_STATE + hh)*D_MODEL + k0 + kk];
    }
    #pragma unroll
    for (int j = 0; j < 4; ++j) {
      int lin = j*256 + t; int rr = lin >> 7, kk = lin & 127;
      Ush[rr][kk] = u[(size_t)(row0+rr)*D_MODEL + k0 + kk];
    }
    __syncthreads();
    #pragma unroll 4
    for (int k = 0; k < 128; ++k) acc += Ush[rs][k] * Wsh[h][k];
    __syncthreads();
  }
  dt[(row0+rs)*NHEADS + h] = softplusf(acc + dt_bias[h]);
}

// A_cum[(b*32+h)*32+c][l]
__global__ __launch_bounds__(64) void acum_kernel(const float* __restrict__ dt,
    const float* __restrict__ A_log, float* __restrict__ A_cum) {
  int blk = blockIdx.x;                             // (b*32+h)*32+c
  int c = blk & 31, h = (blk >> 5) & 31, b = blk >> 10;
  int l = threadIdx.x;
  __shared__ float sv[64];
  int row = b*LSEQ + c*CHUNK + l;
  float a = -expf(A_log[h]);
  sv[l] = a * dt[row*NHEADS + h];
  __syncthreads();
  if (l == 0) {
    float s = 0.f;
    for (int i=0;i<64;++i){ s += sv[i]; sv[i] = s; }
  }
  __syncthreads();
  A_cum[blk*64 + l] = sv[l];
}

// causal depthwise conv (K=4) + bias + silu; fp16 in/out; 8 rows x 4 channels per thread
__global__ __launch_bounds__(256) void conv8_kernel(const unsigned short* __restrict__ zx,
    const float* __restrict__ w, const float* __restrict__ bias, unsigned short* __restrict__ xBC) {
  int idx = blockIdx.x*256 + threadIdx.x;           // over (BL/8) * (CONV_DIM/4)
  if (idx >= (BL/8)*(CONV_DIM/4)) return;
  int c4  = idx % (CONV_DIM/4);
  int rb  = idx / (CONV_DIM/4);
  int ch  = c4 * 4;
  int row0 = rb * 8;
  int l0   = row0 & (LSEQ-1);
  float4 r[11];
  #pragma unroll
  for (int jj=0;jj<11;++jj){
    int li = l0 + jj - 3;
    if (li >= 0) {
      ushort4 v = *(const ushort4*)&zx[(size_t)(row0 + jj - 3)*DPROJ + D_INNER + ch];
      r[jj] = make_float4(h2f(v.x), h2f(v.y), h2f(v.z), h2f(v.w));
    } else r[jj] = make_float4(0.f,0.f,0.f,0.f);
  }
  float4 wv[4];
  #pragma unroll
  for (int c=0;c<4;++c) wv[c] = *(const float4*)&w[(ch+c)*4];
  float4 bv = *(const float4*)&bias[ch];
  #pragma unroll
  for (int j=0;j<8;++j){
    float4 acc = bv;
    acc.x += wv[0].x*r[j].x + wv[0].y*r[j+1].x + wv[0].z*r[j+2].x + wv[0].w*r[j+3].x;
    acc.y += wv[1].x*r[j].y + wv[1].y*r[j+1].y + wv[1].z*r[j+2].y + wv[1].w*r[j+3].y;
    acc.z += wv[2].x*r[j].z + wv[2].y*r[j+1].z + wv[2].z*r[j+2].z + wv[2].w*r[j+3].z;
    acc.w += wv[3].x*r[j].w + wv[3].y*r[j+1].w + wv[3].z*r[j+2].w + wv[3].w*r[j+3].w;
    ushort4 o; o.x=f2h(siluf(acc.x)); o.y=f2h(siluf(acc.y)); o.z=f2h(siluf(acc.z)); o.w=f2h(siluf(acc.w));
    *(ushort4*)&xBC[(size_t)(row0+j)*CONV_DIM + ch] = o;
  }
}

// G[b,c][l][s] = sum_n C[l,n] * B[s,n]; 4 blocks per (b,c)
__global__ __launch_bounds__(256) void g_kernel(const unsigned short* __restrict__ xBC, float* __restrict__ G) {
  int blk = blockIdx.x >> 2;                        // b*32 + c
  int lq  = blockIdx.x & 3;
  int b = blk >> 5, c = blk & 31;
  __shared__ float Bsh[64][129];
  int t = threadIdx.x;
  int row0 = b*LSEQ + c*CHUNK;
  for (int j=0;j<32;++j){
    int lin = j*256 + t;
    int s = lin >> 7, n = lin & 127;
    Bsh[s][n] = h2f(xBC[(size_t)(row0+s)*CONV_DIM + D_INNER + n]);
  }
  __syncthreads();
  int l = lq*16 + (t >> 4), s0 = (t & 15) * 4;
  const unsigned short* Cp = &xBC[(size_t)(row0+l)*CONV_DIM + D_INNER + D_STATE];
  float acc[4] = {};
  for (int n=0;n<128;++n){
    float cv = h2f(Cp[n]);
    #pragma unroll
    for (int j=0;j<4;++j) acc[j] += cv * Bsh[s0+j][n];
  }
  float* Gp = &G[(size_t)blk*4096 + l*64 + s0];
  #pragma unroll
  for (int j=0;j<4;++j) Gp[j] = acc[j];
}

// ---------- MFMA states ----------
__global__ __launch_bounds__(256) void states_mfma(const unsigned short* __restrict__ xBC,
    const float* __restrict__ dt, const float* __restrict__ A_cum, float* __restrict__ states) {
  int blk = blockIdx.x;                             // (b*32+c)*32+h
  int h = blk & 31, c = (blk>>5)&31, b = blk>>10;
  __shared__ _Float16 Bt[128][72];                  // [n][s]
  __shared__ _Float16 xdT[64][72];                  // [p][s]
  __shared__ float Ac[64], dtl[64];
  int t = threadIdx.x;
  int wid = t >> 6, ln = t & 63;
  int row0 = b*LSEQ + c*CHUNK;
  if (t < 64){ Ac[t] = A_cum[((b*32+h)*32 + c)*64 + t]; dtl[t] = dt[(row0+t)*NHEADS + h]; }
  __syncthreads();
  float AcL = Ac[63];
  #pragma unroll
  for (int j=0;j<32;++j){
    int lin = j*256+t; int s = lin>>7, n = lin&127;
    Bt[n][s] = h2h(xBC[(size_t)(row0+s)*CONV_DIM + D_INNER + n]);
  }
  #pragma unroll
  for (int j=0;j<16;++j){
    int lin = j*256+t; int s = lin>>6, p = lin&63;
    xdT[p][s] = (_Float16)(h2f(xBC[(size_t)(row0+s)*CONV_DIM + h*HEADDIM + p]) * dtl[s] * expf(AcL - Ac[s]));
  }
  __syncthreads();
  const int fr = ln & 15, fk = (ln >> 4) * 8;
  f32x4 acc[4][2] = {};
  #pragma unroll
  for (int ks = 0; ks < 2; ++ks){
    half8 a[4], bb[2];
    #pragma unroll
    for (int pt=0;pt<4;++pt) a[pt] = *(const half8*)&xdT[pt*16+fr][ks*32+fk];
    #pragma unroll
    for (int nt=0;nt<2;++nt) bb[nt] = *(const half8*)&Bt[(wid*2+nt)*16+fr][ks*32+fk];
    #pragma unroll
    for (int pt=0;pt<4;++pt)
      #pragma unroll
      for (int nt=0;nt<2;++nt)
        acc[pt][nt] = __builtin_amdgcn_mfma_f32_16x16x32_f16(a[pt], bb[nt], acc[pt][nt], 0, 0, 0);
  }
  float* Sp = &states[(size_t)blk*8192];
  #pragma unroll
  for (int pt=0;pt<4;++pt){
    int p0 = pt*16 + (ln>>4)*4;
    #pragma unroll
    for (int nt=0;nt<2;++nt){
      int n = (wid*2+nt)*16 + fr;
      #pragma unroll
      for (int j=0;j<4;++j) Sp[(p0+j)*128 + n] = acc[pt][nt][j];
    }
  }
}

// inter-chunk scan, split 8-way over the 8192 state elements
__global__ __launch_bounds__(256) void scan_kernel(const float* __restrict__ A_cum,
                                                   float* __restrict__ states) {
  int g  = blockIdx.x & 7;
  int bh = blockIdx.x >> 3;
  int b = bh >> 5, h = bh & 31;
  int t = threadIdx.x;
  float S[4];
  #pragma unroll
  for (int j=0;j<4;++j) S[j] = 0.f;
  for (int c=0;c<NCHUNK;++c){
    float decay = expf(A_cum[((b*32+h)*32 + c)*64 + 63]);
    float* Sp = &states[(size_t)((b*32+c)*32 + h)*8192];
    #pragma unroll
    for (int j=0;j<4;++j){
      float tmp = Sp[(g*4+j)*256+t];
      Sp[(g*4+j)*256+t] = S[j];
      S[j] = S[j]*decay + tmp;
    }
  }
}

// ---------- MFMA Y ----------
__global__ __launch_bounds__(256) void y_mfma(const unsigned short* __restrict__ xBC,
    const unsigned short* __restrict__ zx, const float* __restrict__ dt,
    const float* __restrict__ A_cum, const float* __restrict__ G,
    const float* __restrict__ states, const float* __restrict__ Dp,
    unsigned short* __restrict__ y_pre) {
  int blk = blockIdx.x;                             // (b*32+c)*32+h
  int h = blk & 31, c = (blk>>5)&31, b = blk>>10;
  __shared__ _Float16 Cl[64][136];
  __shared__ _Float16 Sin[64][136];
  __shared__ _Float16 Ms[64][72];
  __shared__ _Float16 xdT[64][72];
  __shared__ float Ac[64], dtl[64];
  int t = threadIdx.x;
  int wid = t >> 6, ln = t & 63;
  int row0 = b*LSEQ + c*CHUNK;
  if (t < 64){ Ac[t] = A_cum[((b*32+h)*32 + c)*64 + t]; dtl[t] = dt[(row0+t)*NHEADS + h]; }
  __syncthreads();
  #pragma unroll
  for (int j=0;j<32;++j){
    int lin = j*256+t; int l = lin>>7, n = lin&127;
    Cl[l][n] = (_Float16)(h2f(xBC[(size_t)(row0+l)*CONV_DIM + D_INNER + D_STATE + n]) * expf(Ac[l]));
  }
  {
    const float* Sg = &states[(size_t)blk*8192];
    #pragma unroll
    for (int j=0;j<32;++j){
      int lin = j*256+t; int p = lin>>7, n = lin&127;
      Sin[p][n] = (_Float16)Sg[lin];
    }
  }
  #pragma unroll
  for (int j=0;j<16;++j){
    int lin = j*256+t; int s = lin>>6, p = lin&63;
    xdT[p][s] = (_Float16)(h2f(xBC[(size_t)(row0+s)*CONV_DIM + h*HEADDIM + p]) * dtl[s]);
  }
  {
    const float* Gp = &G[(size_t)(b*32+c)*4096];
    #pragma unroll
    for (int j=0;j<16;++j){
      int lin = j*256+t; int l = lin>>6, s = lin&63;
      Ms[l][s] = (s <= l) ? (_Float16)(Gp[l*64+s] * expf(Ac[l]-Ac[s])) : (_Float16)0.f;
    }
  }
  __syncthreads();
  const int wr = wid >> 1, wc = wid & 1;
  const int fr = ln & 15, fk = (ln >> 4) * 8;
  f32x4 acc[2][2] = {};
  #pragma unroll
  for (int ks = 0; ks < 4; ++ks){
    half8 a[2], bb[2];
    #pragma unroll
    for (int lt=0;lt<2;++lt) a[lt] = *(const half8*)&Cl[(wr*2+lt)*16+fr][ks*32+fk];
    #pragma unroll
    for (int pt=0;pt<2;++pt) bb[pt] = *(const half8*)&Sin[(wc*2+pt)*16+fr][ks*32+fk];
    #pragma unroll
    for (int lt=0;lt<2;++lt)
      #pragma unroll
      for (int pt=0;pt<2;++pt)
        acc[lt][pt] = __builtin_amdgcn_mfma_f32_16x16x32_f16(a[lt], bb[pt], acc[lt][pt], 0, 0, 0);
  }
  #pragma unroll
  for (int ks = 0; ks < 2; ++ks){
    half8 a[2], bb[2];
    #pragma unroll
    for (int lt=0;lt<2;++lt) a[lt] = *(const half8*)&Ms[(wr*2+lt)*16+fr][ks*32+fk];
    #pragma unroll
    for (int pt=0;pt<2;++pt) bb[pt] = *(const half8*)&xdT[(wc*2+pt)*16+fr][ks*32+fk];
    #pragma unroll
    for (int lt=0;lt<2;++lt)
      #pragma unroll
      for (int pt=0;pt<2;++pt)
        acc[lt][pt] = __builtin_amdgcn_mfma_f32_16x16x32_f16(a[lt], bb[pt], acc[lt][pt], 0, 0, 0);
  }
  float Dh = Dp[h];
  #pragma unroll
  for (int lt=0;lt<2;++lt){
    int l0 = (wr*2+lt)*16 + (ln>>4)*4;
    #pragma unroll
    for (int pt=0;pt<2;++pt){
      int p = (wc*2+pt)*16 + fr;
      #pragma unroll
      for (int j=0;j<4;++j){
        int grow = row0 + l0 + j;
        float x = h2f(xBC[(size_t)grow*CONV_DIM + h*HEADDIM + p]);
        float z = h2f(zx[(size_t)grow*DPROJ + h*HEADDIM + p]);
        y_pre[(size_t)grow*D_INNER + h*HEADDIM + p] = f2h((acc[lt][pt][j] + x*Dh) * siluf(z));
      }
    }
  }
}

// RMS norm * norm_w, fp16 in -> fp16 out, contiguous 8/thread
__global__ __launch_bounds__(256) void rms_kernel(const unsigned short* __restrict__ y,
    const float* __restrict__ norm_w, unsigned short* __restrict__ yh) {
  int row = blockIdx.x;
  int t = threadIdx.x;
  const unsigned short* yr = y + (size_t)row*D_INNER + t*8;
  ushort4 a = *(const ushort4*)yr;
  ushort4 bq = *(const ushort4*)(yr+4);
  float v[8];
  v[0]=h2f(a.x); v[1]=h2f(a.y); v[2]=h2f(a.z); v[3]=h2f(a.w);
  v[4]=h2f(bq.x); v[5]=h2f(bq.y); v[6]=h2f(bq.z); v[7]=h2f(bq.w);
  float ss = 0.f;
  #pragma unroll
  for (int j=0;j<8;++j) ss += v[j]*v[j];
  #pragma unroll
  for (int off=32; off>0; off>>=1) ss += __shfl_down(ss, off, 64);
  __shared__ float wsum[4];
  int wid = t >> 6, lane = t & 63;
  if (lane == 0) wsum[wid] = ss;
  __syncthreads();
  if (t == 0) wsum[0] = rsqrtf((wsum[0]+wsum[1]+wsum[2]+wsum[3])/D_INNER + EPSF);
  __syncthreads();
  float sc = wsum[0];
  float4 w0 = *(const float4*)&norm_w[t*8];
  float4 w1 = *(const float4*)&norm_w[t*8+4];
  ushort4 o0, o1;
  o0.x=f2h(v[0]*sc*w0.x); o0.y=f2h(v[1]*sc*w0.y); o0.z=f2h(v[2]*sc*w0.z); o0.w=f2h(v[3]*sc*w0.w);
  o1.x=f2h(v[4]*sc*w1.x); o1.y=f2h(v[5]*sc*w1.y); o1.z=f2h(v[6]*sc*w1.z); o1.w=f2h(v[7]*sc*w1.w);
  unsigned short* yo = yh + (size_t)row*D_INNER + t*8;
  *(ushort4*)yo = o0;
  *(ushort4*)(yo+4) = o1;
}

extern "C" void kernel_launch(void* const* d_in, const int* in_sizes, int n_in,
                              void* d_out, int out_size, void* d_ws, size_t ws_size,
                              hipStream_t stream) {
  const float* u       = (const float*)d_in[0];
  const float* W_in    = (const float*)d_in[1];
  const float* conv_w  = (const float*)d_in[2];
  const float* conv_b  = (const float*)d_in[3];
  const float* dt_bias = (const float*)d_in[4];
  const float* A_log   = (const float*)d_in[5];
  const float* Dp      = (const float*)d_in[6];
  const float* norm_w  = (const float*)d_in[7];
  const float* W_out   = (const float*)d_in[8];
  float* out = (float*)d_out;

  char* w = (char*)d_ws;
  unsigned short* zx_h   = (unsigned short*)w;  w += (size_t)BL*DPROJ*2;    // 35.9 MB
  unsigned short* xBC_h  = (unsigned short*)w;  w += (size_t)BL*CONV_DIM*2; // 18.9 MB
  unsigned short* ypre_h = (unsigned short*)w;  w += (size_t)BL*D_INNER*2;  // 16.8 MB
  unsigned short* y_h    = (unsigned short*)w;  w += (size_t)BL*D_INNER*2;  // 16.8 MB
  unsigned short* u_h    = (unsigned short*)w;  w += (size_t)BL*D_MODEL*2;  //  8.4 MB
  unsigned short* Win_h  = (unsigned short*)w;  w += (size_t)NPAD1*D_MODEL*2;// 9.2 MB
  unsigned short* Wout_h = (unsigned short*)w;  w += (size_t)D_MODEL*D_INNER*2; // 4.2 MB
  float* dt     = (float*)w;  w += (size_t)BL*NHEADS*4;
  float* A_cum  = (float*)w;  w += (size_t)B_SZ*NHEADS*NCHUNK*CHUNK*4;
  float* G      = (float*)w;  w += (size_t)B_SZ*NCHUNK*CHUNK*CHUNK*4;
  float* states = (float*)w;  w += (size_t)B_SZ*NCHUNK*NHEADS*HEADDIM*D_STATE*4; // 67.1 MB

  // converts (no ordering constraints — all dedicated buffers)
  cvt_f16<<<(BL*D_MODEL/4)/256, 256, 0, stream>>>(u, u_h, BL*D_MODEL/4);
  cvt_pad<<<((NPAD1*D_MODEL/4)+255)/256, 256, 0, stream>>>(W_in, Win_h, DPROJ, NPAD1*D_MODEL/4, D_MODEL/4);
  cvt_f16<<<(D_MODEL*D_INNER/4)/256, 256, 0, stream>>>(W_out, Wout_h, D_MODEL*D_INNER/4);
  // 1) zxbcdt = u @ W_in.T  (fp16 out)
  gemm_f16_pipe<1><<<dim3(NPAD1/128, BL/128), 256, 0, stream>>>(u_h, Win_h, zx_h, DPROJ, D_MODEL);
  // 2) dt exact in fp32
  dt_gemm<<<BL/8, 256, 0, stream>>>(u, W_in, dt_bias, dt);
  // 3) per-chunk cumsum of A*dt
  acum_kernel<<<B_SZ*NHEADS*NCHUNK, 64, 0, stream>>>(dt, A_log, A_cum);
  // 4) depthwise conv + silu (fp16 in/out)
  conv8_kernel<<<((BL/8)*(CONV_DIM/4)+255)/256, 256, 0, stream>>>(zx_h, conv_w, conv_b, xBC_h);
  // 5) G = C B^T per (b,c)
  g_kernel<<<B_SZ*NCHUNK*4, 256, 0, stream>>>(xBC_h, G);
  // 6) per-chunk states (MFMA)
  states_mfma<<<B_SZ*NCHUNK*NHEADS, 256, 0, stream>>>(xBC_h, dt, A_cum, states);
  // 7) inter-chunk scan, 8-way split
  scan_kernel<<<B_SZ*NHEADS*8, 256, 0, stream>>>(A_cum, states);
  // 8) Y (MFMA), fp16 out
  y_mfma<<<B_SZ*NCHUNK*NHEADS, 256, 0, stream>>>(xBC_h, zx_h, dt, A_cum, G, states, Dp, ypre_h);
  // 9) RMS norm fp16->fp16
  rms_kernel<<<BL, 256, 0, stream>>>(ypre_h, norm_w, y_h);
  // 10) out = y @ W_out.T (fp32 out)
  gemm_f16_pipe<0><<<dim3(D_MODEL/128, BL/128), 256, 0, stream>>>(y_h, Wout_h, out, D_MODEL, D_INNER);
}

// Round 9
// 235.411 us; speedup vs baseline: 6.3717x; 1.1526x over previous
//
#include <hip/hip_runtime.h>
#include <hip/hip_bf16.h>
#include <math.h>

#define D_MODEL 1024
#define D_INNER 2048
#define D_STATE 128
#define NHEADS 32
#define HEADDIM 64
#define CHUNK 64
#define B_SZ 2
#define LSEQ 2048
#define BL (B_SZ*LSEQ)                              // 4096
#define DPROJ (2*D_INNER + 2*D_STATE + NHEADS)      // 4384
#define CONV_DIM (D_INNER + 2*D_STATE)              // 2304
#define NCHUNK (LSEQ/CHUNK)                         // 32
#define NPAD1 4480                                  // DPROJ padded to x128
#define EPSF 1e-5f

typedef __attribute__((ext_vector_type(8))) _Float16 half8;
typedef __attribute__((ext_vector_type(4))) _Float16 half4;
typedef __attribute__((ext_vector_type(4))) float f32x4;

__device__ __forceinline__ float siluf(float v){ return v / (1.0f + expf(-v)); }
__device__ __forceinline__ float softplusf(float v){ return v > 20.0f ? v : log1pf(expf(v)); }
__device__ __forceinline__ unsigned short f2h(float x){
  union { _Float16 h; unsigned short u; } v; v.h = (_Float16)x;
  return v.u;
}
__device__ __forceinline__ float h2f(unsigned short x){
  union { unsigned short u; _Float16 h; } v; v.u = x;
  return (float)v.h;
}
__device__ __forceinline__ _Float16 h2h(unsigned short x){
  union { unsigned short u; _Float16 h; } v; v.u = x;
  return v.h;
}

typedef const __attribute__((address_space(1))) void gvoid_t;
typedef __attribute__((address_space(3))) void lvoid_t;
__device__ __forceinline__ void gl_lds16(const void* gsrc, void* ldst) {
  gvoid_t* g = reinterpret_cast<gvoid_t*>((uintptr_t)gsrc);
  lvoid_t* l = reinterpret_cast<lvoid_t*>((unsigned int)(uintptr_t)ldst);
  __builtin_amdgcn_global_load_lds(g, l, 16, 0, 0);
}

// ---------- fp32 -> fp16 converters ----------
__global__ void cvt_f16(const float* __restrict__ in, unsigned short* __restrict__ out, int n4) {
  int i = blockIdx.x*256 + threadIdx.x;
  if (i >= n4) return;
  float4 v = *(const float4*)(in + (size_t)i*4);
  ushort4 o; o.x=f2h(v.x); o.y=f2h(v.y); o.z=f2h(v.z); o.w=f2h(v.w);
  *(ushort4*)(out + (size_t)i*4) = o;
}

__global__ void cvt_pad(const float* __restrict__ in, unsigned short* __restrict__ out,
                        int rows_in, int total4, int kdim4) {
  int i = blockIdx.x*256 + threadIdx.x;
  if (i >= total4) return;
  int row = i / kdim4;
  ushort4 o; o.x=0; o.y=0; o.z=0; o.w=0;
  if (row < rows_in) {
    float4 v = *(const float4*)(in + (size_t)i*4);
    o.x=f2h(v.x); o.y=f2h(v.y); o.z=f2h(v.z); o.w=f2h(v.w);
  }
  *(ushort4*)(out + (size_t)i*4) = o;
}

// ---------- pipelined fp16 MFMA GEMM; 4 slots, prefetch depth 3 ----------
template<int OUT_F16>
__global__ __launch_bounds__(256) void gemm_f16_pipe(const unsigned short* __restrict__ A,
    const unsigned short* __restrict__ W, void* __restrict__ Cv, int N, int K) {
  __shared__ unsigned short lds[4*2*4096];          // 64 KB
  const int t   = threadIdx.x;
  const int wid = t >> 6, l = t & 63;
  const int nwg = gridDim.x * gridDim.y;
  int bid = blockIdx.y * gridDim.x + blockIdx.x;
  int swz = (bid & 7) * (nwg >> 3) + (bid >> 3);    // XCD-chunked (nwg%8==0)
  const int m0 = (swz / gridDim.x) * 128;
  const int n0 = (swz % gridDim.x) * 128;
  const int wr = wid >> 1, wc = wid & 1;
  const int fr = l & 15, cg = l >> 4;
  const int NT = K >> 5;

  int srow[2]; int scol[2];
  #pragma unroll
  for (int i=0;i<2;++i){
    int s = i*256 + t;
    int r = s >> 2, c = s & 3;
    int sw = (r + (r>>2)) & 3;
    srow[i] = r; scol[i] = (c ^ sw) * 8;
  }
  const unsigned short* Abase = A + (size_t)m0 * K;
  const unsigned short* Wbase = W + (size_t)n0 * K;

#define STAGE(tt, slot) { \
    int kk = (tt) << 5; \
    unsigned short* La = &lds[(slot)*8192]; \
    unsigned short* Lb = &lds[(slot)*8192 + 4096]; \
    gl_lds16(Abase + (size_t)srow[0]*K + kk + scol[0], (char*)La + (0*256+t)*16); \
    gl_lds16(Abase + (size_t)srow[1]*K + kk + scol[1], (char*)La + (1*256+t)*16); \
    gl_lds16(Wbase + (size_t)srow[0]*K + kk + scol[0], (char*)Lb + (0*256+t)*16); \
    gl_lds16(Wbase + (size_t)srow[1]*K + kk + scol[1], (char*)Lb + (1*256+t)*16); \
  }

  f32x4 acc[4][4] = {};
  STAGE(0, 0);
  STAGE(1, 1);
  STAGE(2, 2);
  asm volatile("s_waitcnt vmcnt(8)" ::: "memory");
  __builtin_amdgcn_s_barrier();
  asm volatile("" ::: "memory");

  for (int tt = 0; tt < NT; ++tt) {
    int slot = tt & 3;
    if (tt + 3 < NT) STAGE(tt+3, (tt+3)&3);
    const unsigned short* La = &lds[slot*8192];
    const unsigned short* Lb = &lds[slot*8192 + 4096];
    half8 af[4], bfv[4];
    #pragma unroll
    for (int m=0;m<4;++m){
      int r = wr*64 + m*16 + fr;
      int sw = (r + (r>>2)) & 3;
      af[m] = *(const half8*)&La[(r*4 + (cg ^ sw))*8];
    }
    #pragma unroll
    for (int n=0;n<4;++n){
      int r = wc*64 + n*16 + fr;
      int sw = (r + (r>>2)) & 3;
      bfv[n] = *(const half8*)&Lb[(r*4 + (cg ^ sw))*8];
    }
    __builtin_amdgcn_s_setprio(1);
    #pragma unroll
    for (int m=0;m<4;++m)
      #pragma unroll
      for (int n=0;n<4;++n)
        acc[m][n] = __builtin_amdgcn_mfma_f32_16x16x32_f16(af[m], bfv[n], acc[m][n], 0, 0, 0);
    __builtin_amdgcn_s_setprio(0);
    if (tt + 1 < NT) {
      if      (tt + 3 < NT) { asm volatile("s_waitcnt vmcnt(8)" ::: "memory"); }
      else if (tt + 2 < NT) { asm volatile("s_waitcnt vmcnt(4)" ::: "memory"); }
      else                  { asm volatile("s_waitcnt vmcnt(0)" ::: "memory"); }
      __builtin_amdgcn_s_barrier();
      asm volatile("" ::: "memory");
    }
  }
#undef STAGE

  const int crow = m0 + wr*64 + (l >> 4) * 4;
  const int ccol0 = n0 + wc*64 + fr;
  #pragma unroll
  for (int m = 0; m < 4; ++m) {
    #pragma unroll
    for (int n = 0; n < 4; ++n) {
      int col = ccol0 + n*16;
      if (col < N) {
        if (OUT_F16) {
          unsigned short* cp = (unsigned short*)Cv + (size_t)(crow + m*16)*N + col;
          #pragma unroll
          for (int j = 0; j < 4; ++j) cp[(size_t)j*N] = f2h(acc[m][n][j]);
        } else {
          float* cp = (float*)Cv + (size_t)(crow + m*16)*N + col;
          #pragma unroll
          for (int j = 0; j < 4; ++j) cp[(size_t)j*N] = acc[m][n][j];
        }
      }
    }
  }
}

// ---------- exact fp32 dt path (float4 LDS) ----------
__global__ __launch_bounds__(256) void dt_gemm(const float* __restrict__ u,
    const float* __restrict__ W_in, const float* __restrict__ dt_bias, float* __restrict__ dt) {
  __shared__ float4 Wsh[32][33];
  __shared__ float4 Ush[8][33];
  int t = threadIdx.x;
  int row0 = blockIdx.x * 8;
  int h = t & 31, rs = t >> 5;
  float acc = 0.f;
  for (int k0 = 0; k0 < D_MODEL; k0 += 128) {
    #pragma unroll
    for (int j = 0; j < 4; ++j) {
      int lin = j*256 + t; int hh = lin >> 5, kk = lin & 31;
      Wsh[hh][kk] = *(const float4*)&W_in[(size_t)(2*D_INNER + 2*D_STATE + hh)*D_MODEL + k0 + kk*4];
    }
    {
      int hh = t >> 5, kk = t & 31;
      Ush[hh][kk] = *(const float4*)&u[(size_t)(row0+hh)*D_MODEL + k0 + kk*4];
    }
    __syncthreads();
    #pragma unroll
    for (int k = 0; k < 32; ++k) {
      float4 a = Ush[rs][k], b = Wsh[h][k];
      acc += a.x*b.x + a.y*b.y + a.z*b.z + a.w*b.w;
    }
    __syncthreads();
  }
  dt[(row0+rs)*NHEADS + h] = softplusf(acc + dt_bias[h]);
}

// A_cum[(b*32+h)*32+c][l]
__global__ __launch_bounds__(64) void acum_kernel(const float* __restrict__ dt,
    const float* __restrict__ A_log, float* __restrict__ A_cum) {
  int blk = blockIdx.x;                             // (b*32+h)*32+c
  int c = blk & 31, h = (blk >> 5) & 31, b = blk >> 10;
  int l = threadIdx.x;
  __shared__ float sv[64];
  int row = b*LSEQ + c*CHUNK + l;
  float a = -expf(A_log[h]);
  sv[l] = a * dt[row*NHEADS + h];
  __syncthreads();
  if (l == 0) {
    float s = 0.f;
    for (int i=0;i<64;++i){ s += sv[i]; sv[i] = s; }
  }
  __syncthreads();
  A_cum[blk*64 + l] = sv[l];
}

// causal depthwise conv (K=4) + bias + silu; fp16 in/out; 8 rows x 4 channels per thread
__global__ __launch_bounds__(256) void conv8_kernel(const unsigned short* __restrict__ zx,
    const float* __restrict__ w, const float* __restrict__ bias, unsigned short* __restrict__ xBC) {
  int idx = blockIdx.x*256 + threadIdx.x;           // over (BL/8) * (CONV_DIM/4)
  if (idx >= (BL/8)*(CONV_DIM/4)) return;
  int c4  = idx % (CONV_DIM/4);
  int rb  = idx / (CONV_DIM/4);
  int ch  = c4 * 4;
  int row0 = rb * 8;
  int l0   = row0 & (LSEQ-1);
  float4 r[11];
  #pragma unroll
  for (int jj=0;jj<11;++jj){
    int li = l0 + jj - 3;
    if (li >= 0) {
      ushort4 v = *(const ushort4*)&zx[(size_t)(row0 + jj - 3)*DPROJ + D_INNER + ch];
      r[jj] = make_float4(h2f(v.x), h2f(v.y), h2f(v.z), h2f(v.w));
    } else r[jj] = make_float4(0.f,0.f,0.f,0.f);
  }
  float4 wv[4];
  #pragma unroll
  for (int c=0;c<4;++c) wv[c] = *(const float4*)&w[(ch+c)*4];
  float4 bv = *(const float4*)&bias[ch];
  #pragma unroll
  for (int j=0;j<8;++j){
    float4 acc = bv;
    acc.x += wv[0].x*r[j].x + wv[0].y*r[j+1].x + wv[0].z*r[j+2].x + wv[0].w*r[j+3].x;
    acc.y += wv[1].x*r[j].y + wv[1].y*r[j+1].y + wv[1].z*r[j+2].y + wv[1].w*r[j+3].y;
    acc.z += wv[2].x*r[j].z + wv[2].y*r[j+1].z + wv[2].z*r[j+2].z + wv[2].w*r[j+3].z;
    acc.w += wv[3].x*r[j].w + wv[3].y*r[j+1].w + wv[3].z*r[j+2].w + wv[3].w*r[j+3].w;
    ushort4 o; o.x=f2h(siluf(acc.x)); o.y=f2h(siluf(acc.y)); o.z=f2h(siluf(acc.z)); o.w=f2h(siluf(acc.w));
    *(ushort4*)&xBC[(size_t)(row0+j)*CONV_DIM + ch] = o;
  }
}

// G[b,c][l][s] = sum_n C[l,n] * B[s,n]; 4 blocks per (b,c)
__global__ __launch_bounds__(256) void g_kernel(const unsigned short* __restrict__ xBC, float* __restrict__ G) {
  int blk = blockIdx.x >> 2;                        // b*32 + c
  int lq  = blockIdx.x & 3;
  int b = blk >> 5, c = blk & 31;
  __shared__ float Bsh[64][129];
  int t = threadIdx.x;
  int row0 = b*LSEQ + c*CHUNK;
  for (int j=0;j<32;++j){
    int lin = j*256 + t;
    int s = lin >> 7, n = lin & 127;
    Bsh[s][n] = h2f(xBC[(size_t)(row0+s)*CONV_DIM + D_INNER + n]);
  }
  __syncthreads();
  int l = lq*16 + (t >> 4), s0 = (t & 15) * 4;
  const unsigned short* Cp = &xBC[(size_t)(row0+l)*CONV_DIM + D_INNER + D_STATE];
  float acc[4] = {};
  for (int n=0;n<128;++n){
    float cv = h2f(Cp[n]);
    #pragma unroll
    for (int j=0;j<4;++j) acc[j] += cv * Bsh[s0+j][n];
  }
  float* Gp = &G[(size_t)blk*4096 + l*64 + s0];
  #pragma unroll
  for (int j=0;j<4;++j) Gp[j] = acc[j];
}

// ---------- MFMA states (fp16 out) ----------
__global__ __launch_bounds__(256) void states_mfma(const unsigned short* __restrict__ xBC,
    const float* __restrict__ dt, const float* __restrict__ A_cum, unsigned short* __restrict__ states) {
  int blk = blockIdx.x;                             // (b*32+c)*32+h
  int h = blk & 31, c = (blk>>5)&31, b = blk>>10;
  __shared__ _Float16 Bt[128][72];                  // [n][s]
  __shared__ _Float16 xdT[64][72];                  // [p][s]
  __shared__ float Ac[64], dtl[64];
  int t = threadIdx.x;
  int wid = t >> 6, ln = t & 63;
  int row0 = b*LSEQ + c*CHUNK;
  if (t < 64){ Ac[t] = A_cum[((b*32+h)*32 + c)*64 + t]; dtl[t] = dt[(row0+t)*NHEADS + h]; }
  __syncthreads();
  float AcL = Ac[63];
  #pragma unroll
  for (int j=0;j<32;++j){
    int lin = j*256+t; int s = lin>>7, n = lin&127;
    Bt[n][s] = h2h(xBC[(size_t)(row0+s)*CONV_DIM + D_INNER + n]);
  }
  #pragma unroll
  for (int j=0;j<16;++j){
    int lin = j*256+t; int s = lin>>6, p = lin&63;
    xdT[p][s] = (_Float16)(h2f(xBC[(size_t)(row0+s)*CONV_DIM + h*HEADDIM + p]) * dtl[s] * expf(AcL - Ac[s]));
  }
  __syncthreads();
  const int fr = ln & 15, fk = (ln >> 4) * 8;
  f32x4 acc[4][2] = {};
  #pragma unroll
  for (int ks = 0; ks < 2; ++ks){
    half8 a[4], bb[2];
    #pragma unroll
    for (int pt=0;pt<4;++pt) a[pt] = *(const half8*)&xdT[pt*16+fr][ks*32+fk];
    #pragma unroll
    for (int nt=0;nt<2;++nt) bb[nt] = *(const half8*)&Bt[(wid*2+nt)*16+fr][ks*32+fk];
    #pragma unroll
    for (int pt=0;pt<4;++pt)
      #pragma unroll
      for (int nt=0;nt<2;++nt)
        acc[pt][nt] = __builtin_amdgcn_mfma_f32_16x16x32_f16(a[pt], bb[nt], acc[pt][nt], 0, 0, 0);
  }
  unsigned short* Sp = &states[(size_t)blk*8192];
  #pragma unroll
  for (int pt=0;pt<4;++pt){
    int p0 = pt*16 + (ln>>4)*4;
    #pragma unroll
    for (int nt=0;nt<2;++nt){
      int n = (wid*2+nt)*16 + fr;
      #pragma unroll
      for (int j=0;j<4;++j) Sp[(p0+j)*128 + n] = f2h(acc[pt][nt][j]);
    }
  }
}

// inter-chunk scan (fp16 storage, fp32 accumulator), split 8-way
__global__ __launch_bounds__(256) void scan_kernel(const float* __restrict__ A_cum,
                                                   unsigned short* __restrict__ states) {
  int g  = blockIdx.x & 7;
  int bh = blockIdx.x >> 3;
  int b = bh >> 5, h = bh & 31;
  int t = threadIdx.x;
  float S[4];
  #pragma unroll
  for (int j=0;j<4;++j) S[j] = 0.f;
  for (int c=0;c<NCHUNK;++c){
    float decay = expf(A_cum[((b*32+h)*32 + c)*64 + 63]);
    unsigned short* Sp = &states[(size_t)((b*32+c)*32 + h)*8192];
    #pragma unroll
    for (int j=0;j<4;++j){
      float tmp = h2f(Sp[(g*4+j)*256+t]);
      Sp[(g*4+j)*256+t] = f2h(S[j]);
      S[j] = S[j]*decay + tmp;
    }
  }
}

// ---------- MFMA Y ----------
__global__ __launch_bounds__(256) void y_mfma(const unsigned short* __restrict__ xBC,
    const unsigned short* __restrict__ zx, const float* __restrict__ dt,
    const float* __restrict__ A_cum, const float* __restrict__ G,
    const unsigned short* __restrict__ states, const float* __restrict__ Dp,
    unsigned short* __restrict__ y_pre) {
  int blk = blockIdx.x;                             // (b*32+c)*32+h
  int h = blk & 31, c = (blk>>5)&31, b = blk>>10;
  __shared__ _Float16 Cl[64][136];
  __shared__ _Float16 Sin[64][136];
  __shared__ _Float16 Ms[64][72];
  __shared__ _Float16 xdT[64][72];
  __shared__ float Ac[64], dtl[64];
  int t = threadIdx.x;
  int wid = t >> 6, ln = t & 63;
  int row0 = b*LSEQ + c*CHUNK;
  if (t < 64){ Ac[t] = A_cum[((b*32+h)*32 + c)*64 + t]; dtl[t] = dt[(row0+t)*NHEADS + h]; }
  __syncthreads();
  #pragma unroll
  for (int j=0;j<32;++j){
    int lin = j*256+t; int l = lin>>7, n = lin&127;
    Cl[l][n] = (_Float16)(h2f(xBC[(size_t)(row0+l)*CONV_DIM + D_INNER + D_STATE + n]) * expf(Ac[l]));
  }
  {
    const unsigned short* Sg = &states[(size_t)blk*8192];
    #pragma unroll
    for (int j=0;j<8;++j){
      int elem = (j*256+t)*4; int p = elem>>7, n = elem&127;
      ushort4 v = *(const ushort4*)&Sg[elem];
      half4 hv = { h2h(v.x), h2h(v.y), h2h(v.z), h2h(v.w) };
      *(half4*)&Sin[p][n] = hv;
    }
  }
  #pragma unroll
  for (int j=0;j<16;++j){
    int lin = j*256+t; int s = lin>>6, p = lin&63;
    xdT[p][s] = (_Float16)(h2f(xBC[(size_t)(row0+s)*CONV_DIM + h*HEADDIM + p]) * dtl[s]);
  }
  {
    const float* Gp = &G[(size_t)(b*32+c)*4096];
    #pragma unroll
    for (int j=0;j<16;++j){
      int lin = j*256+t; int l = lin>>6, s = lin&63;
      Ms[l][s] = (s <= l) ? (_Float16)(Gp[l*64+s] * expf(Ac[l]-Ac[s])) : (_Float16)0.f;
    }
  }
  __syncthreads();
  const int wr = wid >> 1, wc = wid & 1;
  const int fr = ln & 15, fk = (ln >> 4) * 8;
  f32x4 acc[2][2] = {};
  #pragma unroll
  for (int ks = 0; ks < 4; ++ks){
    half8 a[2], bb[2];
    #pragma unroll
    for (int lt=0;lt<2;++lt) a[lt] = *(const half8*)&Cl[(wr*2+lt)*16+fr][ks*32+fk];
    #pragma unroll
    for (int pt=0;pt<2;++pt) bb[pt] = *(const half8*)&Sin[(wc*2+pt)*16+fr][ks*32+fk];
    #pragma unroll
    for (int lt=0;lt<2;++lt)
      #pragma unroll
      for (int pt=0;pt<2;++pt)
        acc[lt][pt] = __builtin_amdgcn_mfma_f32_16x16x32_f16(a[lt], bb[pt], acc[lt][pt], 0, 0, 0);
  }
  #pragma unroll
  for (int ks = 0; ks < 2; ++ks){
    half8 a[2], bb[2];
    #pragma unroll
    for (int lt=0;lt<2;++lt) a[lt] = *(const half8*)&Ms[(wr*2+lt)*16+fr][ks*32+fk];
    #pragma unroll
    for (int pt=0;pt<2;++pt) bb[pt] = *(const half8*)&xdT[(wc*2+pt)*16+fr][ks*32+fk];
    #pragma unroll
    for (int lt=0;lt<2;++lt)
      #pragma unroll
      for (int pt=0;pt<2;++pt)
        acc[lt][pt] = __builtin_amdgcn_mfma_f32_16x16x32_f16(a[lt], bb[pt], acc[lt][pt], 0, 0, 0);
  }
  float Dh = Dp[h];
  #pragma unroll
  for (int lt=0;lt<2;++lt){
    int l0 = (wr*2+lt)*16 + (ln>>4)*4;
    #pragma unroll
    for (int pt=0;pt<2;++pt){
      int p = (wc*2+pt)*16 + fr;
      #pragma unroll
      for (int j=0;j<4;++j){
        int grow = row0 + l0 + j;
        float x = h2f(xBC[(size_t)grow*CONV_DIM + h*HEADDIM + p]);
        float z = h2f(zx[(size_t)grow*DPROJ + h*HEADDIM + p]);
        y_pre[(size_t)grow*D_INNER + h*HEADDIM + p] = f2h((acc[lt][pt][j] + x*Dh) * siluf(z));
      }
    }
  }
}

// RMS norm * norm_w, fp16 in -> fp16 out, contiguous 8/thread
__global__ __launch_bounds__(256) void rms_kernel(const unsigned short* __restrict__ y,
    const float* __restrict__ norm_w, unsigned short* __restrict__ yh) {
  int row = blockIdx.x;
  int t = threadIdx.x;
  const unsigned short* yr = y + (size_t)row*D_INNER + t*8;
  ushort4 a = *(const ushort4*)yr;
  ushort4 bq = *(const ushort4*)(yr+4);
  float v[8];
  v[0]=h2f(a.x); v[1]=h2f(a.y); v[2]=h2f(a.z); v[3]=h2f(a.w);
  v[4]=h2f(bq.x); v[5]=h2f(bq.y); v[6]=h2f(bq.z); v[7]=h2f(bq.w);
  float ss = 0.f;
  #pragma unroll
  for (int j=0;j<8;++j) ss += v[j]*v[j];
  #pragma unroll
  for (int off=32; off>0; off>>=1) ss += __shfl_down(ss, off, 64);
  __shared__ float wsum[4];
  int wid = t >> 6, lane = t & 63;
  if (lane == 0) wsum[wid] = ss;
  __syncthreads();
  if (t == 0) wsum[0] = rsqrtf((wsum[0]+wsum[1]+wsum[2]+wsum[3])/D_INNER + EPSF);
  __syncthreads();
  float sc = wsum[0];
  float4 w0 = *(const float4*)&norm_w[t*8];
  float4 w1 = *(const float4*)&norm_w[t*8+4];
  ushort4 o0, o1;
  o0.x=f2h(v[0]*sc*w0.x); o0.y=f2h(v[1]*sc*w0.y); o0.z=f2h(v[2]*sc*w0.z); o0.w=f2h(v[3]*sc*w0.w);
  o1.x=f2h(v[4]*sc*w1.x); o1.y=f2h(v[5]*sc*w1.y); o1.z=f2h(v[6]*sc*w1.z); o1.w=f2h(v[7]*sc*w1.w);
  unsigned short* yo = yh + (size_t)row*D_INNER + t*8;
  *(ushort4*)yo = o0;
  *(ushort4*)(yo+4) = o1;
}

extern "C" void kernel_launch(void* const* d_in, const int* in_sizes, int n_in,
                              void* d_out, int out_size, void* d_ws, size_t ws_size,
                              hipStream_t stream) {
  const float* u       = (const float*)d_in[0];
  const float* W_in    = (const float*)d_in[1];
  const float* conv_w  = (const float*)d_in[2];
  const float* conv_b  = (const float*)d_in[3];
  const float* dt_bias = (const float*)d_in[4];
  const float* A_log   = (const float*)d_in[5];
  const float* Dp      = (const float*)d_in[6];
  const float* norm_w  = (const float*)d_in[7];
  const float* W_out   = (const float*)d_in[8];
  float* out = (float*)d_out;

  char* w = (char*)d_ws;
  unsigned short* zx_h   = (unsigned short*)w;  w += (size_t)BL*DPROJ*2;    // 35.9 MB
  unsigned short* xBC_h  = (unsigned short*)w;  w += (size_t)BL*CONV_DIM*2; // 18.9 MB
  unsigned short* ypre_h = (unsigned short*)w;  w += (size_t)BL*D_INNER*2;  // 16.8 MB
  unsigned short* y_h    = (unsigned short*)w;  w += (size_t)BL*D_INNER*2;  // 16.8 MB
  unsigned short* u_h    = (unsigned short*)w;  w += (size_t)BL*D_MODEL*2;  //  8.4 MB
  unsigned short* Win_h  = (unsigned short*)w;  w += (size_t)NPAD1*D_MODEL*2;// 9.2 MB
  unsigned short* Wout_h = (unsigned short*)w;  w += (size_t)D_MODEL*D_INNER*2; // 4.2 MB
  unsigned short* states = (unsigned short*)w;  w += (size_t)B_SZ*NCHUNK*NHEADS*HEADDIM*D_STATE*2; // 33.5 MB
  float* dt     = (float*)w;  w += (size_t)BL*NHEADS*4;
  float* A_cum  = (float*)w;  w += (size_t)B_SZ*NHEADS*NCHUNK*CHUNK*4;
  float* G      = (float*)w;  w += (size_t)B_SZ*NCHUNK*CHUNK*CHUNK*4;

  cvt_f16<<<(BL*D_MODEL/4)/256, 256, 0, stream>>>(u, u_h, BL*D_MODEL/4);
  cvt_pad<<<((NPAD1*D_MODEL/4)+255)/256, 256, 0, stream>>>(W_in, Win_h, DPROJ, NPAD1*D_MODEL/4, D_MODEL/4);
  cvt_f16<<<(D_MODEL*D_INNER/4)/256, 256, 0, stream>>>(W_out, Wout_h, D_MODEL*D_INNER/4);
  // 1) zxbcdt = u @ W_in.T  (fp16 out)
  gemm_f16_pipe<1><<<dim3(NPAD1/128, BL/128), 256, 0, stream>>>(u_h, Win_h, zx_h, DPROJ, D_MODEL);
  // 2) dt exact in fp32
  dt_gemm<<<BL/8, 256, 0, stream>>>(u, W_in, dt_bias, dt);
  // 3) per-chunk cumsum of A*dt
  acum_kernel<<<B_SZ*NHEADS*NCHUNK, 64, 0, stream>>>(dt, A_log, A_cum);
  // 4) depthwise conv + silu (fp16 in/out)
  conv8_kernel<<<((BL/8)*(CONV_DIM/4)+255)/256, 256, 0, stream>>>(zx_h, conv_w, conv_b, xBC_h);
  // 5) G = C B^T per (b,c)
  g_kernel<<<B_SZ*NCHUNK*4, 256, 0, stream>>>(xBC_h, G);
  // 6) per-chunk states (MFMA, fp16 out)
  states_mfma<<<B_SZ*NCHUNK*NHEADS, 256, 0, stream>>>(xBC_h, dt, A_cum, states);
  // 7) inter-chunk scan, 8-way split (fp16 storage)
  scan_kernel<<<B_SZ*NHEADS*8, 256, 0, stream>>>(A_cum, states);
  // 8) Y (MFMA), fp16 out
  y_mfma<<<B_SZ*NCHUNK*NHEADS, 256, 0, stream>>>(xBC_h, zx_h, dt, A_cum, G, states, Dp, ypre_h);
  // 9) RMS norm fp16->fp16
  rms_kernel<<<BL, 256, 0, stream>>>(ypre_h, norm_w, y_h);
  // 10) out = y @ W_out.T (fp32 out)
  gemm_f16_pipe<0><<<dim3(D_MODEL/128, BL/128), 256, 0, stream>>>(y_h, Wout_h, out, D_MODEL, D_INNER);
}

// Round 10
// 210.706 us; speedup vs baseline: 7.1188x; 1.1172x over previous
//
#include <hip/hip_runtime.h>
#include <hip/hip_bf16.h>
#include <math.h>

#define D_MODEL 1024
#define D_INNER 2048
#define D_STATE 128
#define NHEADS 32
#define HEADDIM 64
#define CHUNK 64
#define B_SZ 2
#define LSEQ 2048
#define BL (B_SZ*LSEQ)                              // 4096
#define DPROJ (2*D_INNER + 2*D_STATE + NHEADS)      // 4384
#define CONV_DIM (D_INNER + 2*D_STATE)              // 2304
#define NCHUNK (LSEQ/CHUNK)                         // 32
#define NPAD1 4480                                  // DPROJ padded to x128
#define EPSF 1e-5f

typedef __attribute__((ext_vector_type(8))) _Float16 half8;
typedef __attribute__((ext_vector_type(4))) _Float16 half4;
typedef __attribute__((ext_vector_type(4))) float f32x4;

__device__ __forceinline__ float siluf(float v){ return v / (1.0f + expf(-v)); }
__device__ __forceinline__ float softplusf(float v){ return v > 20.0f ? v : log1pf(expf(v)); }
__device__ __forceinline__ unsigned short f2h(float x){
  union { _Float16 h; unsigned short u; } v; v.h = (_Float16)x;
  return v.u;
}
__device__ __forceinline__ float h2f(unsigned short x){
  union { unsigned short u; _Float16 h; } v; v.u = x;
  return (float)v.h;
}
__device__ __forceinline__ _Float16 h2h(unsigned short x){
  union { unsigned short u; _Float16 h; } v; v.u = x;
  return v.h;
}

typedef const __attribute__((address_space(1))) void gvoid_t;
typedef __attribute__((address_space(3))) void lvoid_t;
__device__ __forceinline__ void gl_lds16(const void* gsrc, void* ldst) {
  gvoid_t* g = reinterpret_cast<gvoid_t*>((uintptr_t)gsrc);
  lvoid_t* l = reinterpret_cast<lvoid_t*>((unsigned int)(uintptr_t)ldst);
  __builtin_amdgcn_global_load_lds(g, l, 16, 0, 0);
}

// ---------- fp32 -> fp16 converters ----------
__global__ void cvt_f16(const float* __restrict__ in, unsigned short* __restrict__ out, int n4) {
  int i = blockIdx.x*256 + threadIdx.x;
  if (i >= n4) return;
  float4 v = *(const float4*)(in + (size_t)i*4);
  ushort4 o; o.x=f2h(v.x); o.y=f2h(v.y); o.z=f2h(v.z); o.w=f2h(v.w);
  *(ushort4*)(out + (size_t)i*4) = o;
}

__global__ void cvt_pad(const float* __restrict__ in, unsigned short* __restrict__ out,
                        int rows_in, int total4, int kdim4) {
  int i = blockIdx.x*256 + threadIdx.x;
  if (i >= total4) return;
  int row = i / kdim4;
  ushort4 o; o.x=0; o.y=0; o.z=0; o.w=0;
  if (row < rows_in) {
    float4 v = *(const float4*)(in + (size_t)i*4);
    o.x=f2h(v.x); o.y=f2h(v.y); o.z=f2h(v.z); o.w=f2h(v.w);
  }
  *(ushort4*)(out + (size_t)i*4) = o;
}

// ---------- pipelined fp16 MFMA GEMM; 5 slots, prefetch depth 4, vmcnt(12) ----------
template<int OUT_F16>
__global__ __launch_bounds__(256) void gemm_f16_pipe(const unsigned short* __restrict__ A,
    const unsigned short* __restrict__ W, void* __restrict__ Cv, int N, int K) {
  __shared__ unsigned short lds[5*2*4096];          // 80 KB -> still 2 blocks/CU
  const int t   = threadIdx.x;
  const int wid = t >> 6, l = t & 63;
  const int nwg = gridDim.x * gridDim.y;
  int bid = blockIdx.y * gridDim.x + blockIdx.x;
  int swz = (bid & 7) * (nwg >> 3) + (bid >> 3);    // XCD-chunked (nwg%8==0)
  const int m0 = (swz / gridDim.x) * 128;
  const int n0 = (swz % gridDim.x) * 128;
  const int wr = wid >> 1, wc = wid & 1;
  const int fr = l & 15, cg = l >> 4;
  const int NT = K >> 5;

  int srow[2]; int scol[2];
  #pragma unroll
  for (int i=0;i<2;++i){
    int s = i*256 + t;
    int r = s >> 2, c = s & 3;
    int sw = (r + (r>>2)) & 3;
    srow[i] = r; scol[i] = (c ^ sw) * 8;
  }
  const unsigned short* Abase = A + (size_t)m0 * K;
  const unsigned short* Wbase = W + (size_t)n0 * K;

#define STAGE(tt, slot) { \
    int kk = (tt) << 5; \
    unsigned short* La = &lds[(slot)*8192]; \
    unsigned short* Lb = &lds[(slot)*8192 + 4096]; \
    gl_lds16(Abase + (size_t)srow[0]*K + kk + scol[0], (char*)La + (0*256+t)*16); \
    gl_lds16(Abase + (size_t)srow[1]*K + kk + scol[1], (char*)La + (1*256+t)*16); \
    gl_lds16(Wbase + (size_t)srow[0]*K + kk + scol[0], (char*)Lb + (0*256+t)*16); \
    gl_lds16(Wbase + (size_t)srow[1]*K + kk + scol[1], (char*)Lb + (1*256+t)*16); \
  }

  f32x4 acc[4][4] = {};
  STAGE(0, 0);
  STAGE(1, 1);
  STAGE(2, 2);
  STAGE(3, 3);
  asm volatile("s_waitcnt vmcnt(12)" ::: "memory");
  __builtin_amdgcn_s_barrier();
  asm volatile("" ::: "memory");

  int cs = 0;                                       // compute slot = tt % 5
  for (int tt = 0; tt < NT; ++tt) {
    int ss = (cs == 0) ? 4 : cs - 1;                // (tt+4) % 5
    if (tt + 4 < NT) STAGE(tt+4, ss);
    const unsigned short* La = &lds[cs*8192];
    const unsigned short* Lb = &lds[cs*8192 + 4096];
    half8 af[4], bfv[4];
    #pragma unroll
    for (int m=0;m<4;++m){
      int r = wr*64 + m*16 + fr;
      int sw = (r + (r>>2)) & 3;
      af[m] = *(const half8*)&La[(r*4 + (cg ^ sw))*8];
    }
    #pragma unroll
    for (int n=0;n<4;++n){
      int r = wc*64 + n*16 + fr;
      int sw = (r + (r>>2)) & 3;
      bfv[n] = *(const half8*)&Lb[(r*4 + (cg ^ sw))*8];
    }
    __builtin_amdgcn_s_setprio(1);
    #pragma unroll
    for (int m=0;m<4;++m)
      #pragma unroll
      for (int n=0;n<4;++n)
        acc[m][n] = __builtin_amdgcn_mfma_f32_16x16x32_f16(af[m], bfv[n], acc[m][n], 0, 0, 0);
    __builtin_amdgcn_s_setprio(0);
    if (tt + 1 < NT) {
      if      (tt + 4 < NT) { asm volatile("s_waitcnt vmcnt(12)" ::: "memory"); }
      else if (tt + 3 < NT) { asm volatile("s_waitcnt vmcnt(8)"  ::: "memory"); }
      else if (tt + 2 < NT) { asm volatile("s_waitcnt vmcnt(4)"  ::: "memory"); }
      else                  { asm volatile("s_waitcnt vmcnt(0)"  ::: "memory"); }
      __builtin_amdgcn_s_barrier();
      asm volatile("" ::: "memory");
    }
    cs = (cs == 4) ? 0 : cs + 1;
  }
#undef STAGE

  const int crow = m0 + wr*64 + (l >> 4) * 4;
  const int ccol0 = n0 + wc*64 + fr;
  #pragma unroll
  for (int m = 0; m < 4; ++m) {
    #pragma unroll
    for (int n = 0; n < 4; ++n) {
      int col = ccol0 + n*16;
      if (col < N) {
        if (OUT_F16) {
          unsigned short* cp = (unsigned short*)Cv + (size_t)(crow + m*16)*N + col;
          #pragma unroll
          for (int j = 0; j < 4; ++j) cp[(size_t)j*N] = f2h(acc[m][n][j]);
        } else {
          float* cp = (float*)Cv + (size_t)(crow + m*16)*N + col;
          #pragma unroll
          for (int j = 0; j < 4; ++j) cp[(size_t)j*N] = acc[m][n][j];
        }
      }
    }
  }
}

// ---------- dt from GEMM1 output: softplus(zx[...,4352+h] + bias) ----------
__global__ void dtx_kernel(const unsigned short* __restrict__ zx,
    const float* __restrict__ dt_bias, float* __restrict__ dt) {
  int i = blockIdx.x*256 + threadIdx.x;             // over BL*NHEADS
  if (i >= BL*NHEADS) return;
  int row = i >> 5, h = i & 31;
  float v = h2f(zx[(size_t)row*DPROJ + (2*D_INNER + 2*D_STATE) + h]) + dt_bias[h];
  dt[i] = softplusf(v);
}

// A_cum[(b*32+h)*32+c][l]
__global__ __launch_bounds__(64) void acum_kernel(const float* __restrict__ dt,
    const float* __restrict__ A_log, float* __restrict__ A_cum) {
  int blk = blockIdx.x;                             // (b*32+h)*32+c
  int c = blk & 31, h = (blk >> 5) & 31, b = blk >> 10;
  int l = threadIdx.x;
  __shared__ float sv[64];
  int row = b*LSEQ + c*CHUNK + l;
  float a = -expf(A_log[h]);
  sv[l] = a * dt[row*NHEADS + h];
  __syncthreads();
  if (l == 0) {
    float s = 0.f;
    for (int i=0;i<64;++i){ s += sv[i]; sv[i] = s; }
  }
  __syncthreads();
  A_cum[blk*64 + l] = sv[l];
}

// causal depthwise conv (K=4) + bias + silu; fp16 in/out; 8 rows x 4 channels per thread
__global__ __launch_bounds__(256) void conv8_kernel(const unsigned short* __restrict__ zx,
    const float* __restrict__ w, const float* __restrict__ bias, unsigned short* __restrict__ xBC) {
  int idx = blockIdx.x*256 + threadIdx.x;           // over (BL/8) * (CONV_DIM/4)
  if (idx >= (BL/8)*(CONV_DIM/4)) return;
  int c4  = idx % (CONV_DIM/4);
  int rb  = idx / (CONV_DIM/4);
  int ch  = c4 * 4;
  int row0 = rb * 8;
  int l0   = row0 & (LSEQ-1);
  float4 r[11];
  #pragma unroll
  for (int jj=0;jj<11;++jj){
    int li = l0 + jj - 3;
    if (li >= 0) {
      ushort4 v = *(const ushort4*)&zx[(size_t)(row0 + jj - 3)*DPROJ + D_INNER + ch];
      r[jj] = make_float4(h2f(v.x), h2f(v.y), h2f(v.z), h2f(v.w));
    } else r[jj] = make_float4(0.f,0.f,0.f,0.f);
  }
  float4 wv[4];
  #pragma unroll
  for (int c=0;c<4;++c) wv[c] = *(const float4*)&w[(ch+c)*4];
  float4 bv = *(const float4*)&bias[ch];
  #pragma unroll
  for (int j=0;j<8;++j){
    float4 acc = bv;
    acc.x += wv[0].x*r[j].x + wv[0].y*r[j+1].x + wv[0].z*r[j+2].x + wv[0].w*r[j+3].x;
    acc.y += wv[1].x*r[j].y + wv[1].y*r[j+1].y + wv[1].z*r[j+2].y + wv[1].w*r[j+3].y;
    acc.z += wv[2].x*r[j].z + wv[2].y*r[j+1].z + wv[2].z*r[j+2].z + wv[2].w*r[j+3].z;
    acc.w += wv[3].x*r[j].w + wv[3].y*r[j+1].w + wv[3].z*r[j+2].w + wv[3].w*r[j+3].w;
    ushort4 o; o.x=f2h(siluf(acc.x)); o.y=f2h(siluf(acc.y)); o.z=f2h(siluf(acc.z)); o.w=f2h(siluf(acc.w));
    *(ushort4*)&xBC[(size_t)(row0+j)*CONV_DIM + ch] = o;
  }
}

// G[b,c][l][s] = sum_n C[l,n] * B[s,n]; 4 blocks per (b,c)
__global__ __launch_bounds__(256) void g_kernel(const unsigned short* __restrict__ xBC, float* __restrict__ G) {
  int blk = blockIdx.x >> 2;                        // b*32 + c
  int lq  = blockIdx.x & 3;
  int b = blk >> 5, c = blk & 31;
  __shared__ float Bsh[64][129];
  int t = threadIdx.x;
  int row0 = b*LSEQ + c*CHUNK;
  for (int j=0;j<32;++j){
    int lin = j*256 + t;
    int s = lin >> 7, n = lin & 127;
    Bsh[s][n] = h2f(xBC[(size_t)(row0+s)*CONV_DIM + D_INNER + n]);
  }
  __syncthreads();
  int l = lq*16 + (t >> 4), s0 = (t & 15) * 4;
  const unsigned short* Cp = &xBC[(size_t)(row0+l)*CONV_DIM + D_INNER + D_STATE];
  float acc[4] = {};
  for (int n=0;n<128;++n){
    float cv = h2f(Cp[n]);
    #pragma unroll
    for (int j=0;j<4;++j) acc[j] += cv * Bsh[s0+j][n];
  }
  float* Gp = &G[(size_t)blk*4096 + l*64 + s0];
  #pragma unroll
  for (int j=0;j<4;++j) Gp[j] = acc[j];
}

// ---------- MFMA states (fp16 out) ----------
__global__ __launch_bounds__(256) void states_mfma(const unsigned short* __restrict__ xBC,
    const float* __restrict__ dt, const float* __restrict__ A_cum, unsigned short* __restrict__ states) {
  int blk = blockIdx.x;                             // (b*32+c)*32+h
  int h = blk & 31, c = (blk>>5)&31, b = blk>>10;
  __shared__ _Float16 Bt[128][72];                  // [n][s]
  __shared__ _Float16 xdT[64][72];                  // [p][s]
  __shared__ float Ac[64], dtl[64];
  int t = threadIdx.x;
  int wid = t >> 6, ln = t & 63;
  int row0 = b*LSEQ + c*CHUNK;
  if (t < 64){ Ac[t] = A_cum[((b*32+h)*32 + c)*64 + t]; dtl[t] = dt[(row0+t)*NHEADS + h]; }
  __syncthreads();
  float AcL = Ac[63];
  #pragma unroll
  for (int j=0;j<32;++j){
    int lin = j*256+t; int s = lin>>7, n = lin&127;
    Bt[n][s] = h2h(xBC[(size_t)(row0+s)*CONV_DIM + D_INNER + n]);
  }
  #pragma unroll
  for (int j=0;j<16;++j){
    int lin = j*256+t; int s = lin>>6, p = lin&63;
    xdT[p][s] = (_Float16)(h2f(xBC[(size_t)(row0+s)*CONV_DIM + h*HEADDIM + p]) * dtl[s] * expf(AcL - Ac[s]));
  }
  __syncthreads();
  const int fr = ln & 15, fk = (ln >> 4) * 8;
  f32x4 acc[4][2] = {};
  #pragma unroll
  for (int ks = 0; ks < 2; ++ks){
    half8 a[4], bb[2];
    #pragma unroll
    for (int pt=0;pt<4;++pt) a[pt] = *(const half8*)&xdT[pt*16+fr][ks*32+fk];
    #pragma unroll
    for (int nt=0;nt<2;++nt) bb[nt] = *(const half8*)&Bt[(wid*2+nt)*16+fr][ks*32+fk];
    #pragma unroll
    for (int pt=0;pt<4;++pt)
      #pragma unroll
      for (int nt=0;nt<2;++nt)
        acc[pt][nt] = __builtin_amdgcn_mfma_f32_16x16x32_f16(a[pt], bb[nt], acc[pt][nt], 0, 0, 0);
  }
  unsigned short* Sp = &states[(size_t)blk*8192];
  #pragma unroll
  for (int pt=0;pt<4;++pt){
    int p0 = pt*16 + (ln>>4)*4;
    #pragma unroll
    for (int nt=0;nt<2;++nt){
      int n = (wid*2+nt)*16 + fr;
      #pragma unroll
      for (int j=0;j<4;++j) Sp[(p0+j)*128 + n] = f2h(acc[pt][nt][j]);
    }
  }
}

// inter-chunk scan (fp16 storage, fp32 accumulator), split 8-way
__global__ __launch_bounds__(256) void scan_kernel(const float* __restrict__ A_cum,
                                                   unsigned short* __restrict__ states) {
  int g  = blockIdx.x & 7;
  int bh = blockIdx.x >> 3;
  int b = bh >> 5, h = bh & 31;
  int t = threadIdx.x;
  float S[4];
  #pragma unroll
  for (int j=0;j<4;++j) S[j] = 0.f;
  for (int c=0;c<NCHUNK;++c){
    float decay = expf(A_cum[((b*32+h)*32 + c)*64 + 63]);
    unsigned short* Sp = &states[(size_t)((b*32+c)*32 + h)*8192];
    #pragma unroll
    for (int j=0;j<4;++j){
      float tmp = h2f(Sp[(g*4+j)*256+t]);
      Sp[(g*4+j)*256+t] = f2h(S[j]);
      S[j] = S[j]*decay + tmp;
    }
  }
}

// ---------- MFMA Y ----------
__global__ __launch_bounds__(256) void y_mfma(const unsigned short* __restrict__ xBC,
    const unsigned short* __restrict__ zx, const float* __restrict__ dt,
    const float* __restrict__ A_cum, const float* __restrict__ G,
    const unsigned short* __restrict__ states, const float* __restrict__ Dp,
    unsigned short* __restrict__ y_pre) {
  int blk = blockIdx.x;                             // (b*32+c)*32+h
  int h = blk & 31, c = (blk>>5)&31, b = blk>>10;
  __shared__ _Float16 Cl[64][136];
  __shared__ _Float16 Sin[64][136];
  __shared__ _Float16 Ms[64][72];
  __shared__ _Float16 xdT[64][72];
  __shared__ float Ac[64], dtl[64];
  int t = threadIdx.x;
  int wid = t >> 6, ln = t & 63;
  int row0 = b*LSEQ + c*CHUNK;
  if (t < 64){ Ac[t] = A_cum[((b*32+h)*32 + c)*64 + t]; dtl[t] = dt[(row0+t)*NHEADS + h]; }
  __syncthreads();
  #pragma unroll
  for (int j=0;j<32;++j){
    int lin = j*256+t; int l = lin>>7, n = lin&127;
    Cl[l][n] = (_Float16)(h2f(xBC[(size_t)(row0+l)*CONV_DIM + D_INNER + D_STATE + n]) * expf(Ac[l]));
  }
  {
    const unsigned short* Sg = &states[(size_t)blk*8192];
    #pragma unroll
    for (int j=0;j<8;++j){
      int elem = (j*256+t)*4; int p = elem>>7, n = elem&127;
      ushort4 v = *(const ushort4*)&Sg[elem];
      half4 hv = { h2h(v.x), h2h(v.y), h2h(v.z), h2h(v.w) };
      *(half4*)&Sin[p][n] = hv;
    }
  }
  #pragma unroll
  for (int j=0;j<16;++j){
    int lin = j*256+t; int s = lin>>6, p = lin&63;
    xdT[p][s] = (_Float16)(h2f(xBC[(size_t)(row0+s)*CONV_DIM + h*HEADDIM + p]) * dtl[s]);
  }
  {
    const float* Gp = &G[(size_t)(b*32+c)*4096];
    #pragma unroll
    for (int j=0;j<16;++j){
      int lin = j*256+t; int l = lin>>6, s = lin&63;
      Ms[l][s] = (s <= l) ? (_Float16)(Gp[l*64+s] * expf(Ac[l]-Ac[s])) : (_Float16)0.f;
    }
  }
  __syncthreads();
  const int wr = wid >> 1, wc = wid & 1;
  const int fr = ln & 15, fk = (ln >> 4) * 8;
  f32x4 acc[2][2] = {};
  #pragma unroll
  for (int ks = 0; ks < 4; ++ks){
    half8 a[2], bb[2];
    #pragma unroll
    for (int lt=0;lt<2;++lt) a[lt] = *(const half8*)&Cl[(wr*2+lt)*16+fr][ks*32+fk];
    #pragma unroll
    for (int pt=0;pt<2;++pt) bb[pt] = *(const half8*)&Sin[(wc*2+pt)*16+fr][ks*32+fk];
    #pragma unroll
    for (int lt=0;lt<2;++lt)
      #pragma unroll
      for (int pt=0;pt<2;++pt)
        acc[lt][pt] = __builtin_amdgcn_mfma_f32_16x16x32_f16(a[lt], bb[pt], acc[lt][pt], 0, 0, 0);
  }
  #pragma unroll
  for (int ks = 0; ks < 2; ++ks){
    half8 a[2], bb[2];
    #pragma unroll
    for (int lt=0;lt<2;++lt) a[lt] = *(const half8*)&Ms[(wr*2+lt)*16+fr][ks*32+fk];
    #pragma unroll
    for (int pt=0;pt<2;++pt) bb[pt] = *(const half8*)&xdT[(wc*2+pt)*16+fr][ks*32+fk];
    #pragma unroll
    for (int lt=0;lt<2;++lt)
      #pragma unroll
      for (int pt=0;pt<2;++pt)
        acc[lt][pt] = __builtin_amdgcn_mfma_f32_16x16x32_f16(a[lt], bb[pt], acc[lt][pt], 0, 0, 0);
  }
  float Dh = Dp[h];
  #pragma unroll
  for (int lt=0;lt<2;++lt){
    int l0 = (wr*2+lt)*16 + (ln>>4)*4;
    #pragma unroll
    for (int pt=0;pt<2;++pt){
      int p = (wc*2+pt)*16 + fr;
      #pragma unroll
      for (int j=0;j<4;++j){
        int grow = row0 + l0 + j;
        float x = h2f(xBC[(size_t)grow*CONV_DIM + h*HEADDIM + p]);
        float z = h2f(zx[(size_t)grow*DPROJ + h*HEADDIM + p]);
        y_pre[(size_t)grow*D_INNER + h*HEADDIM + p] = f2h((acc[lt][pt][j] + x*Dh) * siluf(z));
      }
    }
  }
}

// RMS norm * norm_w, fp16 in -> fp16 out, contiguous 8/thread
__global__ __launch_bounds__(256) void rms_kernel(const unsigned short* __restrict__ y,
    const float* __restrict__ norm_w, unsigned short* __restrict__ yh) {
  int row = blockIdx.x;
  int t = threadIdx.x;
  const unsigned short* yr = y + (size_t)row*D_INNER + t*8;
  ushort4 a = *(const ushort4*)yr;
  ushort4 bq = *(const ushort4*)(yr+4);
  float v[8];
  v[0]=h2f(a.x); v[1]=h2f(a.y); v[2]=h2f(a.z); v[3]=h2f(a.w);
  v[4]=h2f(bq.x); v[5]=h2f(bq.y); v[6]=h2f(bq.z); v[7]=h2f(bq.w);
  float ss = 0.f;
  #pragma unroll
  for (int j=0;j<8;++j) ss += v[j]*v[j];
  #pragma unroll
  for (int off=32; off>0; off>>=1) ss += __shfl_down(ss, off, 64);
  __shared__ float wsum[4];
  int wid = t >> 6, lane = t & 63;
  if (lane == 0) wsum[wid] = ss;
  __syncthreads();
  if (t == 0) wsum[0] = rsqrtf((wsum[0]+wsum[1]+wsum[2]+wsum[3])/D_INNER + EPSF);
  __syncthreads();
  float sc = wsum[0];
  float4 w0 = *(const float4*)&norm_w[t*8];
  float4 w1 = *(const float4*)&norm_w[t*8+4];
  ushort4 o0, o1;
  o0.x=f2h(v[0]*sc*w0.x); o0.y=f2h(v[1]*sc*w0.y); o0.z=f2h(v[2]*sc*w0.z); o0.w=f2h(v[3]*sc*w0.w);
  o1.x=f2h(v[4]*sc*w1.x); o1.y=f2h(v[5]*sc*w1.y); o1.z=f2h(v[6]*sc*w1.z); o1.w=f2h(v[7]*sc*w1.w);
  unsigned short* yo = yh + (size_t)row*D_INNER + t*8;
  *(ushort4*)yo = o0;
  *(ushort4*)(yo+4) = o1;
}

extern "C" void kernel_launch(void* const* d_in, const int* in_sizes, int n_in,
                              void* d_out, int out_size, void* d_ws, size_t ws_size,
                              hipStream_t stream) {
  const float* u       = (const float*)d_in[0];
  const float* W_in    = (const float*)d_in[1];
  const float* conv_w  = (const float*)d_in[2];
  const float* conv_b  = (const float*)d_in[3];
  const float* dt_bias = (const float*)d_in[4];
  const float* A_log   = (const float*)d_in[5];
  const float* Dp      = (const float*)d_in[6];
  const float* norm_w  = (const float*)d_in[7];
  const float* W_out   = (const float*)d_in[8];
  float* out = (float*)d_out;

  char* w = (char*)d_ws;
  unsigned short* zx_h   = (unsigned short*)w;  w += (size_t)BL*DPROJ*2;    // 35.9 MB
  unsigned short* xBC_h  = (unsigned short*)w;  w += (size_t)BL*CONV_DIM*2; // 18.9 MB
  unsigned short* ypre_h = (unsigned short*)w;  w += (size_t)BL*D_INNER*2;  // 16.8 MB
  unsigned short* y_h    = (unsigned short*)w;  w += (size_t)BL*D_INNER*2;  // 16.8 MB
  unsigned short* u_h    = (unsigned short*)w;  w += (size_t)BL*D_MODEL*2;  //  8.4 MB
  unsigned short* Win_h  = (unsigned short*)w;  w += (size_t)NPAD1*D_MODEL*2;// 9.2 MB
  unsigned short* Wout_h = (unsigned short*)w;  w += (size_t)D_MODEL*D_INNER*2; // 4.2 MB
  unsigned short* states = (unsigned short*)w;  w += (size_t)B_SZ*NCHUNK*NHEADS*HEADDIM*D_STATE*2; // 33.5 MB
  float* dt     = (float*)w;  w += (size_t)BL*NHEADS*4;
  float* A_cum  = (float*)w;  w += (size_t)B_SZ*NHEADS*NCHUNK*CHUNK*4;
  float* G      = (float*)w;  w += (size_t)B_SZ*NCHUNK*CHUNK*CHUNK*4;

  cvt_f16<<<(BL*D_MODEL/4)/256, 256, 0, stream>>>(u, u_h, BL*D_MODEL/4);
  cvt_pad<<<((NPAD1*D_MODEL/4)+255)/256, 256, 0, stream>>>(W_in, Win_h, DPROJ, NPAD1*D_MODEL/4, D_MODEL/4);
  cvt_f16<<<(D_MODEL*D_INNER/4)/256, 256, 0, stream>>>(W_out, Wout_h, D_MODEL*D_INNER/4);
  // 1) zxbcdt = u @ W_in.T  (fp16 out; includes dt logit columns)
  gemm_f16_pipe<1><<<dim3(NPAD1/128, BL/128), 256, 0, stream>>>(u_h, Win_h, zx_h, DPROJ, D_MODEL);
  // 2) dt = softplus(logits + bias) from GEMM1 output
  dtx_kernel<<<(BL*NHEADS+255)/256, 256, 0, stream>>>(zx_h, dt_bias, dt);
  // 3) per-chunk cumsum of A*dt
  acum_kernel<<<B_SZ*NHEADS*NCHUNK, 64, 0, stream>>>(dt, A_log, A_cum);
  // 4) depthwise conv + silu (fp16 in/out)
  conv8_kernel<<<((BL/8)*(CONV_DIM/4)+255)/256, 256, 0, stream>>>(zx_h, conv_w, conv_b, xBC_h);
  // 5) G = C B^T per (b,c)
  g_kernel<<<B_SZ*NCHUNK*4, 256, 0, stream>>>(xBC_h, G);
  // 6) per-chunk states (MFMA, fp16 out)
  states_mfma<<<B_SZ*NCHUNK*NHEADS, 256, 0, stream>>>(xBC_h, dt, A_cum, states);
  // 7) inter-chunk scan, 8-way split (fp16 storage)
  scan_kernel<<<B_SZ*NHEADS*8, 256, 0, stream>>>(A_cum, states);
  // 8) Y (MFMA), fp16 out
  y_mfma<<<B_SZ*NCHUNK*NHEADS, 256, 0, stream>>>(xBC_h, zx_h, dt, A_cum, G, states, Dp, ypre_h);
  // 9) RMS norm fp16->fp16
  rms_kernel<<<BL, 256, 0, stream>>>(ypre_h, norm_w, y_h);
  // 10) out = y @ W_out.T (fp32 out)
  gemm_f16_pipe<0><<<dim3(D_MODEL/128, BL/128), 256, 0, stream>>>(y_h, Wout_h, out, D_MODEL, D_INNER);
}